// Round 3
// baseline (728.048 us; speedup 1.0000x reference)
//
#include <hip/hip_runtime.h>
#include <hip/hip_bf16.h>

#define N_NODES 16000
#define N_EDGES 128000
#define GATD 768
#define NODED 32
#define EDGED 16
#define METAIN 800
#define METAD 128
#define YCOLS 384   // [y1 (128) | y2 (128) | yself (128)]

// ---------------- small linears ----------------

// Wcat[k][c] : c<128 -> W_nbr[k][c] (dst part); 128<=c<256 -> W_nbr[800+k][c-128] (src part);
//              c>=256 -> W_self[k][c-256]
__global__ __launch_bounds__(256) void pack_kernel(const float* __restrict__ W_nbr,
                                                   const float* __restrict__ W_self,
                                                   float* __restrict__ Wcat){
    int idx = blockIdx.x*256 + threadIdx.x;           // < 800*384
    int k = idx / YCOLS, c = idx % YCOLS;
    float v;
    if (c < 128)      v = W_nbr[(size_t)k*METAD + c];
    else if (c < 256) v = W_nbr[(size_t)(800+k)*METAD + (c-128)];
    else              v = W_self[(size_t)k*METAD + (c-256)];
    Wcat[(size_t)k*YCOLS + c] = v;
}

// ea_lin = edge_attr @ W_edge + b_edge   [E,16]
__global__ __launch_bounds__(256) void ea_kernel(const float* __restrict__ edge_attr,
                                                 const float* __restrict__ W_edge,
                                                 const float* __restrict__ b_edge,
                                                 float* __restrict__ ea_lin){
    __shared__ float We[256];
    __shared__ float be[16];
    int tid = threadIdx.x;
    We[tid] = W_edge[tid];
    if (tid < 16) be[tid] = b_edge[tid];
    __syncthreads();
    int idx = blockIdx.x*256 + tid;                   // < E*16
    int e = idx >> 4, j = idx & 15;
    const float* row = edge_attr + (size_t)e*EDGED;
    float s = be[j];
    #pragma unroll
    for (int k = 0; k < 16; ++k) s += row[k] * We[k*16 + j];
    ea_lin[idx] = s;
}

// nf = node_feature @ W_node + b_node, written into x[:, 768:800]
__global__ __launch_bounds__(256) void nf_kernel(const float* __restrict__ node_feature,
                                                 const float* __restrict__ W_node,
                                                 const float* __restrict__ b_node,
                                                 float* __restrict__ x){
    __shared__ float Wn[1024];
    __shared__ float bn[32];
    int tid = threadIdx.x;
    for (int i = tid; i < 1024; i += 256) Wn[i] = W_node[i];
    if (tid < 32) bn[tid] = b_node[tid];
    __syncthreads();
    int idx = blockIdx.x*256 + tid;                   // < N*32
    int n = idx >> 5, j = idx & 31;
    const float* row = node_feature + (size_t)n*NODED;
    float s = bn[j];
    #pragma unroll
    for (int k = 0; k < 32; ++k) s += row[k] * Wn[k*32 + j];
    x[(size_t)n*METAIN + GATD + j] = s;
}

// ---------------- CSR build ----------------

__global__ __launch_bounds__(256) void deg_kernel(const int* __restrict__ dst, int* __restrict__ deg){
    int e = blockIdx.x*256 + threadIdx.x;
    atomicAdd(&deg[dst[e]], 1);
}

__global__ __launch_bounds__(1024) void scan_kernel(const int* __restrict__ deg,
                                                    int* __restrict__ rowstart,
                                                    int* __restrict__ cursor){
    __shared__ int part[1024];
    int t = threadIdx.x;
    int base = t * 16;
    int local[16];
    int s = 0;
    #pragma unroll
    for (int k = 0; k < 16; ++k){
        int idx = base + k;
        int v = (idx < N_NODES) ? deg[idx] : 0;
        local[k] = s; s += v;
    }
    part[t] = s;
    __syncthreads();
    for (int off = 1; off < 1024; off <<= 1){
        int v = 0;
        if (t >= off) v = part[t-off];
        __syncthreads();
        if (t >= off) part[t] += v;
        __syncthreads();
    }
    int excl = (t == 0) ? 0 : part[t-1];
    #pragma unroll
    for (int k = 0; k < 16; ++k){
        int idx = base + k;
        if (idx < N_NODES){ int rs = excl + local[k]; rowstart[idx] = rs; cursor[idx] = rs; }
    }
    if (t == 1023) rowstart[N_NODES] = part[1023];
}

__global__ __launch_bounds__(256) void csr_kernel(const int* __restrict__ dst,
                                                  int* __restrict__ cursor,
                                                  int* __restrict__ csr){
    int e = blockIdx.x*256 + threadIdx.x;
    int p = atomicAdd(&cursor[dst[e]], 1);
    csr[p] = e;
}

// ---------------- GEMM (64x64 tile, BK=16, 256 thr, 4x4 micro, f32) ----------------

__global__ __launch_bounds__(256) void gemm_f32_kernel(const float* __restrict__ A,
                                                       const float* __restrict__ B,
                                                       float* __restrict__ C,
                                                       int M, int Nc, int K){
    __shared__ float As[16][64];
    __shared__ float Bs[16][64];
    int tid = threadIdx.x;
    int nb = Nc >> 6;
    int bx = blockIdx.x % nb, by = blockIdx.x / nb;
    int tx = tid & 15, ty = tid >> 4;
    int am = tid >> 2, ak = (tid & 3) << 2;
    int bk = tid >> 4, bn = (tid & 15) << 2;
    const float* Aptr = A + (size_t)(by*64 + am)*K + ak;
    const float* Bptr = B + (size_t)bk*Nc + bx*64 + bn;
    float acc[4][4] = {};
    for (int k0 = 0; k0 < K; k0 += 16){
        float4 av = *reinterpret_cast<const float4*>(Aptr + k0);
        float4 bv = *reinterpret_cast<const float4*>(Bptr + (size_t)k0*Nc);
        __syncthreads();
        As[ak+0][am] = av.x; As[ak+1][am] = av.y; As[ak+2][am] = av.z; As[ak+3][am] = av.w;
        *reinterpret_cast<float4*>(&Bs[bk][bn]) = bv;
        __syncthreads();
        #pragma unroll
        for (int kk = 0; kk < 16; ++kk){
            float4 a = *reinterpret_cast<const float4*>(&As[kk][ty<<2]);
            float4 b = *reinterpret_cast<const float4*>(&Bs[kk][tx<<2]);
            acc[0][0]+=a.x*b.x; acc[0][1]+=a.x*b.y; acc[0][2]+=a.x*b.z; acc[0][3]+=a.x*b.w;
            acc[1][0]+=a.y*b.x; acc[1][1]+=a.y*b.y; acc[1][2]+=a.y*b.z; acc[1][3]+=a.y*b.w;
            acc[2][0]+=a.z*b.x; acc[2][1]+=a.z*b.y; acc[2][2]+=a.z*b.z; acc[2][3]+=a.z*b.w;
            acc[3][0]+=a.w*b.x; acc[3][1]+=a.w*b.y; acc[3][2]+=a.w*b.z; acc[3][3]+=a.w*b.w;
        }
    }
    int r0 = by*64 + (ty<<2), c0 = bx*64 + (tx<<2);
    #pragma unroll
    for (int i = 0; i < 4; ++i){
        float4 st = make_float4(acc[i][0], acc[i][1], acc[i][2], acc[i][3]);
        *reinterpret_cast<float4*>(&C[(size_t)(r0+i)*Nc + c0]) = st;
    }
}

// ---------------- attention ----------------

// a_src[n] = h[n]·att_src ; a_dst[n] = h[n]·att_dst   (one wave per row)
__global__ __launch_bounds__(256) void attn_dots_kernel(const float* __restrict__ h,
                                                        const float* __restrict__ att_src,
                                                        const float* __restrict__ att_dst,
                                                        float* __restrict__ a_src,
                                                        float* __restrict__ a_dst){
    int w = threadIdx.x >> 6, lane = threadIdx.x & 63;
    int n = blockIdx.x*4 + w;
    const float* hr = h + (size_t)n*GATD;
    float s = 0.f, d = 0.f;
    #pragma unroll
    for (int j = lane; j < GATD; j += 64){
        float hv = hr[j];
        s += hv * att_src[j];
        d += hv * att_dst[j];
    }
    #pragma unroll
    for (int off = 32; off; off >>= 1){ s += __shfl_xor(s, off); d += __shfl_xor(d, off); }
    if (lane == 0){ a_src[n] = s; a_dst[n] = d; }
}

// per edge: ex = exp(leaky_relu(a_src[src]+a_dst[dst])); denom[dst] += ex
// (max-subtraction skipped: |alpha| << 1 so exp is safe; mathematically identical)
__global__ __launch_bounds__(256) void edge_ex_kernel(const int* __restrict__ src,
                                                      const int* __restrict__ dst,
                                                      const float* __restrict__ a_src,
                                                      const float* __restrict__ a_dst,
                                                      float* __restrict__ ex,
                                                      float* __restrict__ denom){
    int e = blockIdx.x*256 + threadIdx.x;
    int s = src[e], d = dst[e];
    float al = a_src[s] + a_dst[d];
    al = al > 0.f ? al : 0.2f*al;
    float ee = expf(al);
    ex[e] = ee;
    atomicAdd(&denom[d], ee);
}

// gat_out: x[i][0:768] = (sum_e ex_e * h[src_e] + ex_self * h[i]) / (denom[i]+ex_self) + b_gat
__global__ __launch_bounds__(256) void gat_gather_kernel(const float* __restrict__ h,
                                                         const float* __restrict__ ex,
                                                         const float* __restrict__ a_src,
                                                         const float* __restrict__ a_dst,
                                                         const float* __restrict__ denom,
                                                         const float* __restrict__ b_gat,
                                                         const int* __restrict__ src,
                                                         const int* __restrict__ rowstart,
                                                         const int* __restrict__ csr,
                                                         float* __restrict__ x){
    __shared__ int   s_src[64];
    __shared__ float s_ex[64];
    int i = blockIdx.x, t = threadIdx.x;
    float asd = a_src[i] + a_dst[i];
    asd = asd > 0.f ? asd : 0.2f*asd;
    float ex_self = expf(asd);
    const float* hi = h + (size_t)i*GATD;
    float acc0 = ex_self*hi[t], acc1 = ex_self*hi[t+256], acc2 = ex_self*hi[t+512];
    int rs = rowstart[i], re = rowstart[i+1];
    for (int p = rs; p < re; p += 64){
        int cnt = min(64, re - p);
        __syncthreads();
        if (t < cnt){ int e = csr[p+t]; s_src[t] = src[e]; s_ex[t] = ex[e]; }
        __syncthreads();
        for (int j = 0; j < cnt; ++j){
            float w = s_ex[j];
            const float* hs = h + (size_t)s_src[j]*GATD;
            acc0 += w*hs[t]; acc1 += w*hs[t+256]; acc2 += w*hs[t+512];
        }
    }
    float inv = 1.f / (denom[i] + ex_self);
    float* xr = x + (size_t)i*METAIN;
    xr[t]     = acc0*inv + b_gat[t];
    xr[t+256] = acc1*inv + b_gat[t+256];
    xr[t+512] = acc2*inv + b_gat[t+512];
}

// ---------------- final aggregation ----------------

// out[i][c] = deg_i*(y1[i][c] + b_nbr[c]) + sum_e (y2[src_e][c] + (ea_lin[e]@W3)[c]) + yself[i][c] + b_self[c]
__global__ __launch_bounds__(128) void out_gather_kernel(const float* __restrict__ y,
                                                         const float* __restrict__ ea_lin,
                                                         const float* __restrict__ W_nbr,
                                                         const float* __restrict__ b_nbr,
                                                         const float* __restrict__ b_self,
                                                         const int* __restrict__ src,
                                                         const int* __restrict__ rowstart,
                                                         const int* __restrict__ csr,
                                                         float* __restrict__ out){
    __shared__ float W3[16*128];
    __shared__ int   s_src[32];
    __shared__ int   s_eid[32];
    __shared__ float s_ea[32*16];
    int i = blockIdx.x, c = threadIdx.x;
    #pragma unroll
    for (int k = 0; k < 16; ++k) W3[k*128 + c] = W_nbr[(size_t)(1600+k)*METAD + c];
    int rs = rowstart[i], re = rowstart[i+1];
    int deg = re - rs;
    float acc = 0.f;
    for (int p = rs; p < re; p += 32){
        int cnt = min(32, re - p);
        __syncthreads();
        if (c < cnt){ int e = csr[p+c]; s_eid[c] = e; s_src[c] = src[e]; }
        __syncthreads();
        for (int idx = c; idx < cnt*16; idx += 128){
            int j = idx >> 4, k = idx & 15;
            s_ea[idx] = ea_lin[(size_t)s_eid[j]*EDGED + k];
        }
        __syncthreads();
        for (int j = 0; j < cnt; ++j){
            acc += y[(size_t)s_src[j]*YCOLS + 128 + c];
            float ez = 0.f;
            #pragma unroll
            for (int k = 0; k < 16; ++k) ez += s_ea[j*16 + k] * W3[k*128 + c];
            acc += ez;
        }
    }
    float y1 = y[(size_t)i*YCOLS + c];
    float ys = y[(size_t)i*YCOLS + 256 + c];
    float outv = (float)deg * (y1 + b_nbr[c]) + acc + ys + b_self[c];
    out[(size_t)i*METAD + c] = outv;
}

// ---------------- launch ----------------

extern "C" void kernel_launch(void* const* d_in, const int* in_sizes, int n_in,
                              void* d_out, int out_size, void* d_ws, size_t ws_size,
                              hipStream_t stream){
    const float* node_feature    = (const float*)d_in[0];
    const float* edge_attr       = (const float*)d_in[1];
    const float* message_feature = (const float*)d_in[2];
    const int*   edge_index      = (const int*)d_in[3];
    const float* W_node = (const float*)d_in[4];
    const float* b_node = (const float*)d_in[5];
    const float* W_edge = (const float*)d_in[6];
    const float* b_edge = (const float*)d_in[7];
    const float* W_gat  = (const float*)d_in[8];
    const float* att_src= (const float*)d_in[9];
    const float* att_dst= (const float*)d_in[10];
    const float* b_gat  = (const float*)d_in[11];
    const float* W_nbr  = (const float*)d_in[12];
    const float* b_nbr  = (const float*)d_in[13];
    const float* W_self = (const float*)d_in[14];
    const float* b_self = (const float*)d_in[15];
    float* out = (float*)d_out;

    char* wsb = (char*)d_ws;
    size_t off = 0;
    auto walloc = [&](size_t bytes)->void*{
        void* p = wsb + off;
        off = (off + bytes + 511) & ~(size_t)511;
        return p;
    };
    float* h      = (float*)walloc((size_t)N_NODES*GATD*4);      // 49.2 MB
    float* x      = (float*)walloc((size_t)N_NODES*METAIN*4);    // 51.2 MB
    float* y      = (float*)walloc((size_t)N_NODES*YCOLS*4);     // 24.6 MB
    float* ea_lin = (float*)walloc((size_t)N_EDGES*EDGED*4);     // 8.2 MB
    float* Wcat   = (float*)walloc((size_t)METAIN*YCOLS*4);      // 1.2 MB
    float* ex     = (float*)walloc((size_t)N_EDGES*4);
    float* a_src  = (float*)walloc((size_t)N_NODES*4);
    float* a_dst  = (float*)walloc((size_t)N_NODES*4);
    float* denom  = (float*)walloc((size_t)N_NODES*4);
    int* deg      = (int*)walloc((size_t)N_NODES*4);
    int* rowstart = (int*)walloc((size_t)(N_NODES+1)*4);
    int* cursor   = (int*)walloc((size_t)N_NODES*4);
    int* csr      = (int*)walloc((size_t)N_EDGES*4);

    const int* src = edge_index;
    const int* dst = edge_index + N_EDGES;

    hipMemsetAsync(deg,   0, (size_t)N_NODES*4, stream);
    hipMemsetAsync(denom, 0, (size_t)N_NODES*4, stream);

    pack_kernel<<<(METAIN*YCOLS)/256, 256, 0, stream>>>(W_nbr, W_self, Wcat);
    ea_kernel<<<(N_EDGES*EDGED)/256, 256, 0, stream>>>(edge_attr, W_edge, b_edge, ea_lin);
    nf_kernel<<<(N_NODES*NODED)/256, 256, 0, stream>>>(node_feature, W_node, b_node, x);
    deg_kernel<<<N_EDGES/256, 256, 0, stream>>>(dst, deg);
    scan_kernel<<<1, 1024, 0, stream>>>(deg, rowstart, cursor);
    csr_kernel<<<N_EDGES/256, 256, 0, stream>>>(dst, cursor, csr);

    // h = mf @ W_gat   [16000 x 768] x [768 x 768]
    gemm_f32_kernel<<<(N_NODES/64)*(GATD/64), 256, 0, stream>>>(message_feature, W_gat, h, N_NODES, GATD, GATD);
    attn_dots_kernel<<<N_NODES/4, 256, 0, stream>>>(h, att_src, att_dst, a_src, a_dst);
    edge_ex_kernel<<<N_EDGES/256, 256, 0, stream>>>(src, dst, a_src, a_dst, ex, denom);
    gat_gather_kernel<<<N_NODES, 256, 0, stream>>>(h, ex, a_src, a_dst, denom, b_gat, src, rowstart, csr, x);

    // y = x @ Wcat     [16000 x 800] x [800 x 384]
    gemm_f32_kernel<<<(N_NODES/64)*(YCOLS/64), 256, 0, stream>>>(x, Wcat, y, N_NODES, YCOLS, METAIN);
    out_gather_kernel<<<N_NODES, 128, 0, stream>>>(y, ea_lin, W_nbr, b_nbr, b_self, src, rowstart, csr, out);
}

// Round 4
// 368.033 us; speedup vs baseline: 1.9782x; 1.9782x over previous
//
#include <hip/hip_runtime.h>

#define N_NODES 16000
#define N_EDGES 128000
#define GATD 768
#define NODED 32
#define EDGED 16
#define METAIN 800
#define METAD 128
#define YCOLS 384   // [y1 (128) | y2 (128) | yself (128)]

typedef short s16x8 __attribute__((ext_vector_type(8)));
typedef float f32x4v __attribute__((ext_vector_type(4)));

__device__ __forceinline__ unsigned short f2bf(float f){
    unsigned u = __float_as_uint(f);
    return (unsigned short)((u + 0x7fffu + ((u >> 16) & 1u)) >> 16);
}

__device__ __forceinline__ void gload16(const void* g, void* l){
    __builtin_amdgcn_global_load_lds((const __attribute__((address_space(1))) void*)g,
                                     (__attribute__((address_space(3))) void*)l, 16, 0, 0);
}

// ---------------- bf16 conversion pre-passes ----------------

// 8 elems/thread f32 -> bf16
__global__ __launch_bounds__(256) void conv_bf16_kernel(const float* __restrict__ in,
                                                        unsigned short* __restrict__ out, int n8){
    int i = blockIdx.x*256 + threadIdx.x;
    if (i >= n8) return;
    const float4* p = reinterpret_cast<const float4*>(in) + (size_t)i*2;
    float4 a = p[0], b = p[1];
    union { unsigned short u[8]; s16x8 v; } o;
    o.u[0]=f2bf(a.x); o.u[1]=f2bf(a.y); o.u[2]=f2bf(a.z); o.u[3]=f2bf(a.w);
    o.u[4]=f2bf(b.x); o.u[5]=f2bf(b.y); o.u[6]=f2bf(b.z); o.u[7]=f2bf(b.w);
    reinterpret_cast<s16x8*>(out)[i] = o.v;
}

// WgT[c][k] = bf16(W_gat[k][c])   (768x768)
__global__ __launch_bounds__(256) void wgat_t_kernel(const float* __restrict__ W_gat,
                                                     unsigned short* __restrict__ WgT){
    int idx = blockIdx.x*256 + threadIdx.x;          // < 768*768
    int c = idx / GATD, k = idx % GATD;
    WgT[idx] = f2bf(W_gat[(size_t)k*GATD + c]);
}

// WcatT[c][k], c<128: W_nbr[k][c]; c<256: W_nbr[800+k][c-128]; else W_self[k][c-256]  (384x800)
__global__ __launch_bounds__(256) void wcat_t_kernel(const float* __restrict__ W_nbr,
                                                     const float* __restrict__ W_self,
                                                     unsigned short* __restrict__ WcatT){
    int idx = blockIdx.x*256 + threadIdx.x;          // < 384*800
    int c = idx / METAIN, k = idx % METAIN;
    float v;
    if (c < 128)      v = W_nbr[(size_t)k*METAD + c];
    else if (c < 256) v = W_nbr[(size_t)(800+k)*METAD + (c-128)];
    else              v = W_self[(size_t)k*METAD + (c-256)];
    WcatT[idx] = f2bf(v);
}

// ---------------- small linears ----------------

// ea_lin = edge_attr @ W_edge + b_edge   [E,16]
__global__ __launch_bounds__(256) void ea_kernel(const float* __restrict__ edge_attr,
                                                 const float* __restrict__ W_edge,
                                                 const float* __restrict__ b_edge,
                                                 float* __restrict__ ea_lin){
    __shared__ float We[256];
    __shared__ float be[16];
    int tid = threadIdx.x;
    We[tid] = W_edge[tid];
    if (tid < 16) be[tid] = b_edge[tid];
    __syncthreads();
    int idx = blockIdx.x*256 + tid;                  // < E*16
    int e = idx >> 4, j = idx & 15;
    const float* row = edge_attr + (size_t)e*EDGED;
    float s = be[j];
    #pragma unroll
    for (int k = 0; k < 16; ++k) s += row[k] * We[k*16 + j];
    ea_lin[idx] = s;
}

// nf = node_feature @ W_node + b_node -> x_bf[:, 768:800] (bf16)
__global__ __launch_bounds__(256) void nf_kernel(const float* __restrict__ node_feature,
                                                 const float* __restrict__ W_node,
                                                 const float* __restrict__ b_node,
                                                 unsigned short* __restrict__ x_bf){
    __shared__ float Wn[1024];
    __shared__ float bn[32];
    int tid = threadIdx.x;
    for (int i = tid; i < 1024; i += 256) Wn[i] = node_feature ? W_node[i] : 0.f;
    if (tid < 32) bn[tid] = b_node[tid];
    __syncthreads();
    int idx = blockIdx.x*256 + tid;                  // < N*32
    int n = idx >> 5, j = idx & 31;
    const float* row = node_feature + (size_t)n*NODED;
    float s = bn[j];
    #pragma unroll
    for (int k = 0; k < 32; ++k) s += row[k] * Wn[k*32 + j];
    x_bf[(size_t)n*METAIN + GATD + j] = f2bf(s);
}

// ---------------- CSR build ----------------

__global__ __launch_bounds__(256) void deg_kernel(const int* __restrict__ dst, int* __restrict__ deg){
    int e = blockIdx.x*256 + threadIdx.x;
    atomicAdd(&deg[dst[e]], 1);
}

__global__ __launch_bounds__(1024) void scan_kernel(const int* __restrict__ deg,
                                                    int* __restrict__ rowstart,
                                                    int* __restrict__ cursor){
    __shared__ int part[1024];
    int t = threadIdx.x;
    int base = t * 16;
    int local[16];
    int s = 0;
    #pragma unroll
    for (int k = 0; k < 16; ++k){
        int idx = base + k;
        int v = (idx < N_NODES) ? deg[idx] : 0;
        local[k] = s; s += v;
    }
    part[t] = s;
    __syncthreads();
    for (int off = 1; off < 1024; off <<= 1){
        int v = 0;
        if (t >= off) v = part[t-off];
        __syncthreads();
        if (t >= off) part[t] += v;
        __syncthreads();
    }
    int excl = (t == 0) ? 0 : part[t-1];
    #pragma unroll
    for (int k = 0; k < 16; ++k){
        int idx = base + k;
        if (idx < N_NODES){ int rs = excl + local[k]; rowstart[idx] = rs; cursor[idx] = rs; }
    }
    if (t == 1023) rowstart[N_NODES] = part[1023];
}

__global__ __launch_bounds__(256) void csr_kernel(const int* __restrict__ dst,
                                                  int* __restrict__ cursor,
                                                  int* __restrict__ csr){
    int e = blockIdx.x*256 + threadIdx.x;
    int p = atomicAdd(&cursor[dst[e]], 1);
    csr[p] = e;
}

// ---------------- MFMA bf16 GEMM: C[M][Ncols] = A[M][K] @ Bt[Ncols][K]^T ----------------
// 128x128 tile, BK=32, 4 waves (2x2), each wave 64x64 = 4x4 frags of 16x16x32.

__global__ __launch_bounds__(256) void mfma_gemm_kernel(const unsigned short* __restrict__ A,
                                                        const unsigned short* __restrict__ Bt,
                                                        float* __restrict__ C,
                                                        int Ncols, int K){
    __shared__ __align__(16) unsigned short As[128*32];
    __shared__ __align__(16) unsigned short Bs[128*32];
    int tid = threadIdx.x;
    int wave = tid >> 6, lane = tid & 63;
    int rowBase = blockIdx.y * 128, colBase = blockIdx.x * 128;
    const unsigned short* gA = A + (size_t)(rowBase + (tid>>2))*K + (tid&3)*8;
    const unsigned short* gB = Bt + (size_t)(colBase + (tid>>2))*K + (tid&3)*8;
    char* lA = (char*)As + tid*16;
    char* lB = (char*)Bs + tid*16;
    int r0 = (wave>>1)*64, c0 = (wave&1)*64;
    int rl = lane & 15, koff = (lane>>4)*8;
    f32x4v acc[4][4] = {};
    for (int k0 = 0; k0 < K; k0 += 32){
        __syncthreads();                 // previous iter's LDS reads done
        gload16(gA + k0,                     lA);
        gload16(gA + (size_t)64*K + k0,      lA + 4096);
        gload16(gB + k0,                     lB);
        gload16(gB + (size_t)64*K + k0,      lB + 4096);
        __syncthreads();                 // drains vmcnt (compiler-inserted) -> tiles ready
        s16x8 af[4], bfr[4];
        #pragma unroll
        for (int mi = 0; mi < 4; ++mi)
            af[mi] = *reinterpret_cast<const s16x8*>(&As[(r0 + mi*16 + rl)*32 + koff]);
        #pragma unroll
        for (int ni = 0; ni < 4; ++ni)
            bfr[ni] = *reinterpret_cast<const s16x8*>(&Bs[(c0 + ni*16 + rl)*32 + koff]);
        #pragma unroll
        for (int mi = 0; mi < 4; ++mi)
            #pragma unroll
            for (int ni = 0; ni < 4; ++ni)
                acc[mi][ni] = __builtin_amdgcn_mfma_f32_16x16x32_bf16(af[mi], bfr[ni], acc[mi][ni], 0, 0, 0);
    }
    int orow = rowBase + r0 + (lane>>4)*4;
    int ocol = colBase + c0 + rl;
    #pragma unroll
    for (int mi = 0; mi < 4; ++mi)
        #pragma unroll
        for (int ni = 0; ni < 4; ++ni){
            float* cp = C + (size_t)(orow + mi*16)*Ncols + ocol + ni*16;
            #pragma unroll
            for (int j = 0; j < 4; ++j) cp[(size_t)j*Ncols] = acc[mi][ni][j];
        }
}

// ---------------- attention ----------------

__global__ __launch_bounds__(256) void attn_dots_kernel(const float* __restrict__ h,
                                                        const float* __restrict__ att_src,
                                                        const float* __restrict__ att_dst,
                                                        float* __restrict__ a_src,
                                                        float* __restrict__ a_dst){
    int w = threadIdx.x >> 6, lane = threadIdx.x & 63;
    int n = blockIdx.x*4 + w;
    const float* hr = h + (size_t)n*GATD;
    float s = 0.f, d = 0.f;
    #pragma unroll
    for (int j = lane; j < GATD; j += 64){
        float hv = hr[j];
        s += hv * att_src[j];
        d += hv * att_dst[j];
    }
    #pragma unroll
    for (int off = 32; off; off >>= 1){ s += __shfl_xor(s, off); d += __shfl_xor(d, off); }
    if (lane == 0){ a_src[n] = s; a_dst[n] = d; }
}

// (max-subtraction skipped: |alpha| << 1 so exp is safe; mathematically identical)
__global__ __launch_bounds__(256) void edge_ex_kernel(const int* __restrict__ src,
                                                      const int* __restrict__ dst,
                                                      const float* __restrict__ a_src,
                                                      const float* __restrict__ a_dst,
                                                      float* __restrict__ ex,
                                                      float* __restrict__ denom){
    int e = blockIdx.x*256 + threadIdx.x;
    int s = src[e], d = dst[e];
    float al = a_src[s] + a_dst[d];
    al = al > 0.f ? al : 0.2f*al;
    float ee = expf(al);
    ex[e] = ee;
    atomicAdd(&denom[d], ee);
}

// gat_out -> x_bf[:, 0:768] (bf16)
__global__ __launch_bounds__(256) void gat_gather_kernel(const float* __restrict__ h,
                                                         const float* __restrict__ ex,
                                                         const float* __restrict__ a_src,
                                                         const float* __restrict__ a_dst,
                                                         const float* __restrict__ denom,
                                                         const float* __restrict__ b_gat,
                                                         const int* __restrict__ src,
                                                         const int* __restrict__ rowstart,
                                                         const int* __restrict__ csr,
                                                         unsigned short* __restrict__ x_bf){
    __shared__ int   s_src[64];
    __shared__ float s_ex[64];
    int i = blockIdx.x, t = threadIdx.x;
    float asd = a_src[i] + a_dst[i];
    asd = asd > 0.f ? asd : 0.2f*asd;
    float ex_self = expf(asd);
    const float* hi = h + (size_t)i*GATD;
    float acc0 = ex_self*hi[t], acc1 = ex_self*hi[t+256], acc2 = ex_self*hi[t+512];
    int rs = rowstart[i], re = rowstart[i+1];
    for (int p = rs; p < re; p += 64){
        int cnt = min(64, re - p);
        __syncthreads();
        if (t < cnt){ int e = csr[p+t]; s_src[t] = src[e]; s_ex[t] = ex[e]; }
        __syncthreads();
        for (int j = 0; j < cnt; ++j){
            float w = s_ex[j];
            const float* hs = h + (size_t)s_src[j]*GATD;
            acc0 += w*hs[t]; acc1 += w*hs[t+256]; acc2 += w*hs[t+512];
        }
    }
    float inv = 1.f / (denom[i] + ex_self);
    unsigned short* xr = x_bf + (size_t)i*METAIN;
    xr[t]     = f2bf(acc0*inv + b_gat[t]);
    xr[t+256] = f2bf(acc1*inv + b_gat[t+256]);
    xr[t+512] = f2bf(acc2*inv + b_gat[t+512]);
}

// ---------------- final aggregation ----------------

__global__ __launch_bounds__(128) void out_gather_kernel(const float* __restrict__ y,
                                                         const float* __restrict__ ea_lin,
                                                         const float* __restrict__ W_nbr,
                                                         const float* __restrict__ b_nbr,
                                                         const float* __restrict__ b_self,
                                                         const int* __restrict__ src,
                                                         const int* __restrict__ rowstart,
                                                         const int* __restrict__ csr,
                                                         float* __restrict__ out){
    __shared__ float W3[16*128];
    __shared__ int   s_src[32];
    __shared__ int   s_eid[32];
    __shared__ float s_ea[32*16];
    int i = blockIdx.x, c = threadIdx.x;
    #pragma unroll
    for (int k = 0; k < 16; ++k) W3[k*128 + c] = W_nbr[(size_t)(1600+k)*METAD + c];
    int rs = rowstart[i], re = rowstart[i+1];
    int deg = re - rs;
    float acc = 0.f;
    for (int p = rs; p < re; p += 32){
        int cnt = min(32, re - p);
        __syncthreads();
        if (c < cnt){ int e = csr[p+c]; s_eid[c] = e; s_src[c] = src[e]; }
        __syncthreads();
        for (int idx = c; idx < cnt*16; idx += 128){
            int j = idx >> 4, k = idx & 15;
            s_ea[idx] = ea_lin[(size_t)s_eid[j]*EDGED + k];
        }
        __syncthreads();
        for (int j = 0; j < cnt; ++j){
            acc += y[(size_t)s_src[j]*YCOLS + 128 + c];
            float ez = 0.f;
            #pragma unroll
            for (int k = 0; k < 16; ++k) ez += s_ea[j*16 + k] * W3[k*128 + c];
            acc += ez;
        }
    }
    float y1 = y[(size_t)i*YCOLS + c];
    float ys = y[(size_t)i*YCOLS + 256 + c];
    float outv = (float)deg * (y1 + b_nbr[c]) + acc + ys + b_self[c];
    out[(size_t)i*METAD + c] = outv;
}

// ---------------- launch ----------------

extern "C" void kernel_launch(void* const* d_in, const int* in_sizes, int n_in,
                              void* d_out, int out_size, void* d_ws, size_t ws_size,
                              hipStream_t stream){
    const float* node_feature    = (const float*)d_in[0];
    const float* edge_attr       = (const float*)d_in[1];
    const float* message_feature = (const float*)d_in[2];
    const int*   edge_index      = (const int*)d_in[3];
    const float* W_node = (const float*)d_in[4];
    const float* b_node = (const float*)d_in[5];
    const float* W_edge = (const float*)d_in[6];
    const float* b_edge = (const float*)d_in[7];
    const float* W_gat  = (const float*)d_in[8];
    const float* att_src= (const float*)d_in[9];
    const float* att_dst= (const float*)d_in[10];
    const float* b_gat  = (const float*)d_in[11];
    const float* W_nbr  = (const float*)d_in[12];
    const float* b_nbr  = (const float*)d_in[13];
    const float* W_self = (const float*)d_in[14];
    const float* b_self = (const float*)d_in[15];
    float* out = (float*)d_out;

    char* wsb = (char*)d_ws;
    size_t off = 0;
    auto walloc = [&](size_t bytes)->void*{
        void* p = wsb + off;
        off = (off + bytes + 511) & ~(size_t)511;
        return p;
    };
    float* h            = (float*)walloc((size_t)N_NODES*GATD*4);           // 49.2 MB
    float* y            = (float*)walloc((size_t)N_NODES*YCOLS*4);          // 24.6 MB
    float* ea_lin       = (float*)walloc((size_t)N_EDGES*EDGED*4);          // 8.2 MB
    unsigned short* A_bf  = (unsigned short*)walloc((size_t)N_NODES*GATD*2);   // 24.6 MB
    unsigned short* x_bf  = (unsigned short*)walloc((size_t)N_NODES*METAIN*2); // 25.6 MB
    unsigned short* WgT   = (unsigned short*)walloc((size_t)GATD*GATD*2);      // 1.2 MB
    unsigned short* WcatT = (unsigned short*)walloc((size_t)YCOLS*METAIN*2);   // 0.6 MB
    float* ex     = (float*)walloc((size_t)N_EDGES*4);
    float* a_src  = (float*)walloc((size_t)N_NODES*4);
    float* a_dst  = (float*)walloc((size_t)N_NODES*4);
    float* denom  = (float*)walloc((size_t)N_NODES*4);
    int* deg      = (int*)walloc((size_t)N_NODES*4);
    int* rowstart = (int*)walloc((size_t)(N_NODES+1)*4);
    int* cursor   = (int*)walloc((size_t)N_NODES*4);
    int* csr      = (int*)walloc((size_t)N_EDGES*4);

    const int* src = edge_index;
    const int* dst = edge_index + N_EDGES;

    hipMemsetAsync(deg,   0, (size_t)N_NODES*4, stream);
    hipMemsetAsync(denom, 0, (size_t)N_NODES*4, stream);

    // conversions
    conv_bf16_kernel<<<(N_NODES*GATD/8 + 255)/256, 256, 0, stream>>>(message_feature, A_bf, N_NODES*GATD/8);
    wgat_t_kernel<<<(GATD*GATD)/256, 256, 0, stream>>>(W_gat, WgT);
    wcat_t_kernel<<<(YCOLS*METAIN)/256, 256, 0, stream>>>(W_nbr, W_self, WcatT);

    ea_kernel<<<(N_EDGES*EDGED)/256, 256, 0, stream>>>(edge_attr, W_edge, b_edge, ea_lin);
    nf_kernel<<<(N_NODES*NODED)/256, 256, 0, stream>>>(node_feature, W_node, b_node, x_bf);
    deg_kernel<<<N_EDGES/256, 256, 0, stream>>>(dst, deg);
    scan_kernel<<<1, 1024, 0, stream>>>(deg, rowstart, cursor);
    csr_kernel<<<N_EDGES/256, 256, 0, stream>>>(dst, cursor, csr);

    // h = mf @ W_gat   [16000 x 768] = [16000 x 768] x [768 x 768]
    mfma_gemm_kernel<<<dim3(GATD/128, N_NODES/128), 256, 0, stream>>>(A_bf, WgT, h, GATD, GATD);
    attn_dots_kernel<<<N_NODES/4, 256, 0, stream>>>(h, att_src, att_dst, a_src, a_dst);
    edge_ex_kernel<<<N_EDGES/256, 256, 0, stream>>>(src, dst, a_src, a_dst, ex, denom);
    gat_gather_kernel<<<N_NODES, 256, 0, stream>>>(h, ex, a_src, a_dst, denom, b_gat, src, rowstart, csr, x_bf);

    // y = x @ Wcat     [16000 x 384] = [16000 x 800] x [800 x 384]
    mfma_gemm_kernel<<<dim3(YCOLS/128, N_NODES/128), 256, 0, stream>>>(x_bf, WcatT, y, YCOLS, METAIN);
    out_gather_kernel<<<N_NODES, 128, 0, stream>>>(y, ea_lin, W_nbr, b_nbr, b_self, src, rowstart, csr, out);
}

// Round 5
// 320.392 us; speedup vs baseline: 2.2724x; 1.1487x over previous
//
#include <hip/hip_runtime.h>

#define N_NODES 16000
#define N_EDGES 128000
#define GATD 768
#define NODED 32
#define EDGED 16
#define METAIN 800
#define METAD 128
#define YCOLS 384   // [y1 (128) | y2 (128) | yself (128)]

typedef short s16x8 __attribute__((ext_vector_type(8)));
typedef float f32x4v __attribute__((ext_vector_type(4)));

__device__ __forceinline__ unsigned short f2bf(float f){
    unsigned u = __float_as_uint(f);
    return (unsigned short)((u + 0x7fffu + ((u >> 16) & 1u)) >> 16);
}
__device__ __forceinline__ float us2f(unsigned short u){ return __uint_as_float(((unsigned)u)<<16); }

__device__ __forceinline__ void gload16(const void* g, void* l){
    __builtin_amdgcn_global_load_lds((const __attribute__((address_space(1))) void*)g,
                                     (__attribute__((address_space(3))) void*)l, 16, 0, 0);
}

// ---------------- bf16 conversion pre-passes ----------------

__global__ __launch_bounds__(256) void conv_bf16_kernel(const float* __restrict__ in,
                                                        unsigned short* __restrict__ out, int n8){
    int i = blockIdx.x*256 + threadIdx.x;
    if (i >= n8) return;
    const float4* p = reinterpret_cast<const float4*>(in) + (size_t)i*2;
    float4 a = p[0], b = p[1];
    union { unsigned short u[8]; s16x8 v; } o;
    o.u[0]=f2bf(a.x); o.u[1]=f2bf(a.y); o.u[2]=f2bf(a.z); o.u[3]=f2bf(a.w);
    o.u[4]=f2bf(b.x); o.u[5]=f2bf(b.y); o.u[6]=f2bf(b.z); o.u[7]=f2bf(b.w);
    reinterpret_cast<s16x8*>(out)[i] = o.v;
}

// WgT[c][k] = bf16(W_gat[k][c])   (768x768)
__global__ __launch_bounds__(256) void wgat_t_kernel(const float* __restrict__ W_gat,
                                                     unsigned short* __restrict__ WgT){
    int idx = blockIdx.x*256 + threadIdx.x;          // < 768*768
    int c = idx / GATD, k = idx % GATD;
    WgT[idx] = f2bf(W_gat[(size_t)k*GATD + c]);
}

// WcatT[c][k]  (384x800)
__global__ __launch_bounds__(256) void wcat_t_kernel(const float* __restrict__ W_nbr,
                                                     const float* __restrict__ W_self,
                                                     unsigned short* __restrict__ WcatT){
    int idx = blockIdx.x*256 + threadIdx.x;          // < 384*800
    int c = idx / METAIN, k = idx % METAIN;
    float v;
    if (c < 128)      v = W_nbr[(size_t)k*METAD + c];
    else if (c < 256) v = W_nbr[(size_t)(800+k)*METAD + (c-128)];
    else              v = W_self[(size_t)k*METAD + (c-256)];
    WcatT[idx] = f2bf(v);
}

// ---------------- small linears ----------------

__global__ __launch_bounds__(256) void ea_kernel(const float* __restrict__ edge_attr,
                                                 const float* __restrict__ W_edge,
                                                 const float* __restrict__ b_edge,
                                                 float* __restrict__ ea_lin){
    __shared__ float We[256];
    __shared__ float be[16];
    int tid = threadIdx.x;
    We[tid] = W_edge[tid];
    if (tid < 16) be[tid] = b_edge[tid];
    __syncthreads();
    int idx = blockIdx.x*256 + tid;                  // < E*16
    int e = idx >> 4, j = idx & 15;
    const float* row = edge_attr + (size_t)e*EDGED;
    float s = be[j];
    #pragma unroll
    for (int k = 0; k < 16; ++k) s += row[k] * We[k*16 + j];
    ea_lin[idx] = s;
}

// nf -> x_bf[:, 768:800] (bf16)
__global__ __launch_bounds__(256) void nf_kernel(const float* __restrict__ node_feature,
                                                 const float* __restrict__ W_node,
                                                 const float* __restrict__ b_node,
                                                 unsigned short* __restrict__ x_bf){
    __shared__ float Wn[1024];
    __shared__ float bn[32];
    int tid = threadIdx.x;
    for (int i = tid; i < 1024; i += 256) Wn[i] = W_node[i];
    if (tid < 32) bn[tid] = b_node[tid];
    __syncthreads();
    int idx = blockIdx.x*256 + tid;                  // < N*32
    int n = idx >> 5, j = idx & 31;
    const float* row = node_feature + (size_t)n*NODED;
    float s = bn[j];
    #pragma unroll
    for (int k = 0; k < 32; ++k) s += row[k] * Wn[k*32 + j];
    x_bf[(size_t)n*METAIN + GATD + j] = f2bf(s);
}

// ---------------- CSR build ----------------

__global__ __launch_bounds__(256) void deg_kernel(const int* __restrict__ dst, int* __restrict__ deg){
    int e = blockIdx.x*256 + threadIdx.x;
    atomicAdd(&deg[dst[e]], 1);
}

__global__ __launch_bounds__(1024) void scan_kernel(const int* __restrict__ deg,
                                                    int* __restrict__ rowstart,
                                                    int* __restrict__ cursor){
    __shared__ int part[1024];
    int t = threadIdx.x;
    int base = t * 16;
    int local[16];
    int s = 0;
    #pragma unroll
    for (int k = 0; k < 16; ++k){
        int idx = base + k;
        int v = (idx < N_NODES) ? deg[idx] : 0;
        local[k] = s; s += v;
    }
    part[t] = s;
    __syncthreads();
    for (int off = 1; off < 1024; off <<= 1){
        int v = 0;
        if (t >= off) v = part[t-off];
        __syncthreads();
        if (t >= off) part[t] += v;
        __syncthreads();
    }
    int excl = (t == 0) ? 0 : part[t-1];
    #pragma unroll
    for (int k = 0; k < 16; ++k){
        int idx = base + k;
        if (idx < N_NODES){ int rs = excl + local[k]; rowstart[idx] = rs; cursor[idx] = rs; }
    }
    if (t == 1023) rowstart[N_NODES] = part[1023];
}

__global__ __launch_bounds__(256) void csr_kernel(const int* __restrict__ dst,
                                                  int* __restrict__ cursor,
                                                  int* __restrict__ csr){
    int e = blockIdx.x*256 + threadIdx.x;
    int p = atomicAdd(&cursor[dst[e]], 1);
    csr[p] = e;
}

// ---------------- MFMA bf16 GEMM: C = A[M][K] @ Bt[Ncols][K]^T ----------------
// 128x128 tile, BK=32, 4 waves (2x2), each wave 64x64 = 4x4 frags of 16x16x32.
// BFOUT: write C as bf16 instead of f32.

template<bool BFOUT>
__global__ __launch_bounds__(256) void mfma_gemm_kernel(const unsigned short* __restrict__ A,
                                                        const unsigned short* __restrict__ Bt,
                                                        float* __restrict__ Cf,
                                                        unsigned short* __restrict__ Cb,
                                                        int Ncols, int K){
    __shared__ __align__(16) unsigned short As[128*32];
    __shared__ __align__(16) unsigned short Bs[128*32];
    int tid = threadIdx.x;
    int wave = tid >> 6, lane = tid & 63;
    int rowBase = blockIdx.y * 128, colBase = blockIdx.x * 128;
    const unsigned short* gA = A + (size_t)(rowBase + (tid>>2))*K + (tid&3)*8;
    const unsigned short* gB = Bt + (size_t)(colBase + (tid>>2))*K + (tid&3)*8;
    char* lA = (char*)As + tid*16;
    char* lB = (char*)Bs + tid*16;
    int r0 = (wave>>1)*64, c0 = (wave&1)*64;
    int rl = lane & 15, koff = (lane>>4)*8;
    f32x4v acc[4][4] = {};
    for (int k0 = 0; k0 < K; k0 += 32){
        __syncthreads();
        gload16(gA + k0,                     lA);
        gload16(gA + (size_t)64*K + k0,      lA + 4096);
        gload16(gB + k0,                     lB);
        gload16(gB + (size_t)64*K + k0,      lB + 4096);
        __syncthreads();
        s16x8 af[4], bfr[4];
        #pragma unroll
        for (int mi = 0; mi < 4; ++mi)
            af[mi] = *reinterpret_cast<const s16x8*>(&As[(r0 + mi*16 + rl)*32 + koff]);
        #pragma unroll
        for (int ni = 0; ni < 4; ++ni)
            bfr[ni] = *reinterpret_cast<const s16x8*>(&Bs[(c0 + ni*16 + rl)*32 + koff]);
        #pragma unroll
        for (int mi = 0; mi < 4; ++mi)
            #pragma unroll
            for (int ni = 0; ni < 4; ++ni)
                acc[mi][ni] = __builtin_amdgcn_mfma_f32_16x16x32_bf16(af[mi], bfr[ni], acc[mi][ni], 0, 0, 0);
    }
    int orow = rowBase + r0 + (lane>>4)*4;
    int ocol = colBase + c0 + rl;
    #pragma unroll
    for (int mi = 0; mi < 4; ++mi)
        #pragma unroll
        for (int ni = 0; ni < 4; ++ni){
            #pragma unroll
            for (int j = 0; j < 4; ++j){
                size_t idx = (size_t)(orow + mi*16 + j)*Ncols + ocol + ni*16;
                if constexpr (BFOUT) Cb[idx] = f2bf(acc[mi][ni][j]);
                else                 Cf[idx] = acc[mi][ni][j];
            }
        }
}

// ---------------- attention ----------------

// a_src[n] = h[n]·att_src ; a_dst[n] = h[n]·att_dst   (one wave per row, bf16 h)
__global__ __launch_bounds__(256) void attn_dots_kernel(const unsigned short* __restrict__ h_bf,
                                                        const float* __restrict__ att_src,
                                                        const float* __restrict__ att_dst,
                                                        float* __restrict__ a_src,
                                                        float* __restrict__ a_dst){
    int w = threadIdx.x >> 6, lane = threadIdx.x & 63;
    int n = blockIdx.x*4 + w;
    const unsigned short* hr = h_bf + (size_t)n*GATD;
    float s = 0.f, d = 0.f;
    #pragma unroll
    for (int c = 0; c < 3; ++c){
        int o = c*256 + lane*4;
        ushort4 v  = *reinterpret_cast<const ushort4*>(hr + o);
        float4 as4 = *reinterpret_cast<const float4*>(att_src + o);
        float4 ad4 = *reinterpret_cast<const float4*>(att_dst + o);
        float f0 = us2f(v.x), f1 = us2f(v.y), f2 = us2f(v.z), f3 = us2f(v.w);
        s += f0*as4.x + f1*as4.y + f2*as4.z + f3*as4.w;
        d += f0*ad4.x + f1*ad4.y + f2*ad4.z + f3*ad4.w;
    }
    #pragma unroll
    for (int off = 32; off; off >>= 1){ s += __shfl_xor(s, off); d += __shfl_xor(d, off); }
    if (lane == 0){ a_src[n] = s; a_dst[n] = d; }
}

// ---------------- GAT aggregate: wave per node, fused edge-softmax ----------------
// x[i][0:768] = (sum_e ex_e*h[src_e] + ex_self*h[i]) / (sum ex + ex_self) + b_gat
// (max-subtraction skipped: |alpha| << 1 so exp is safe; mathematically identical)

__global__ __launch_bounds__(256) void gat_gather_kernel(const unsigned short* __restrict__ h_bf,
                                                         const float* __restrict__ a_src,
                                                         const float* __restrict__ a_dst,
                                                         const float* __restrict__ b_gat,
                                                         const int* __restrict__ src,
                                                         const int* __restrict__ rowstart,
                                                         const int* __restrict__ csr,
                                                         unsigned short* __restrict__ x_bf){
    int wv = threadIdx.x >> 6, lane = threadIdx.x & 63;
    int i = blockIdx.x*4 + wv;
    float adi = a_dst[i];
    float al = a_src[i] + adi;
    al = al > 0.f ? al : 0.2f*al;
    float ex_self = expf(al);
    const unsigned short* hi = h_bf + (size_t)i*GATD;
    float acc[12];
    #pragma unroll
    for (int c = 0; c < 3; ++c){
        ushort4 v = *reinterpret_cast<const ushort4*>(hi + c*256 + lane*4);
        acc[c*4+0] = ex_self*us2f(v.x); acc[c*4+1] = ex_self*us2f(v.y);
        acc[c*4+2] = ex_self*us2f(v.z); acc[c*4+3] = ex_self*us2f(v.w);
    }
    float dsum = ex_self;
    int rs = rowstart[i], re = rowstart[i+1];
    for (int p = rs; p < re; p += 64){
        int cnt = min(64, re - p);
        int sv = 0; float ev = 0.f;
        if (lane < cnt){
            int e = csr[p+lane];
            sv = src[e];
            float a = a_src[sv] + adi;
            a = a > 0.f ? a : 0.2f*a;
            ev = expf(a);
        }
        for (int j = 0; j < cnt; ++j){
            int   ss = __shfl(sv, j);
            float ww = __shfl(ev, j);
            dsum += ww;
            const unsigned short* hs = h_bf + (size_t)ss*GATD;
            #pragma unroll
            for (int c = 0; c < 3; ++c){
                ushort4 v = *reinterpret_cast<const ushort4*>(hs + c*256 + lane*4);
                acc[c*4+0] += ww*us2f(v.x); acc[c*4+1] += ww*us2f(v.y);
                acc[c*4+2] += ww*us2f(v.z); acc[c*4+3] += ww*us2f(v.w);
            }
        }
    }
    float inv = 1.f / dsum;
    unsigned short* xr = x_bf + (size_t)i*METAIN;
    #pragma unroll
    for (int c = 0; c < 3; ++c){
        float4 bg = *reinterpret_cast<const float4*>(b_gat + c*256 + lane*4);
        ushort4 o;
        o.x = f2bf(acc[c*4+0]*inv + bg.x); o.y = f2bf(acc[c*4+1]*inv + bg.y);
        o.z = f2bf(acc[c*4+2]*inv + bg.z); o.w = f2bf(acc[c*4+3]*inv + bg.w);
        *reinterpret_cast<ushort4*>(xr + c*256 + lane*4) = o;
    }
}

// ---------------- final aggregation ----------------

__global__ __launch_bounds__(128) void out_gather_kernel(const float* __restrict__ y,
                                                         const float* __restrict__ ea_lin,
                                                         const float* __restrict__ W_nbr,
                                                         const float* __restrict__ b_nbr,
                                                         const float* __restrict__ b_self,
                                                         const int* __restrict__ src,
                                                         const int* __restrict__ rowstart,
                                                         const int* __restrict__ csr,
                                                         float* __restrict__ out){
    __shared__ float W3[16*128];
    __shared__ int   s_src[32];
    __shared__ int   s_eid[32];
    __shared__ float s_ea[32*16];
    int i = blockIdx.x, c = threadIdx.x;
    #pragma unroll
    for (int k = 0; k < 16; ++k) W3[k*128 + c] = W_nbr[(size_t)(1600+k)*METAD + c];
    int rs = rowstart[i], re = rowstart[i+1];
    int deg = re - rs;
    float acc = 0.f;
    for (int p = rs; p < re; p += 32){
        int cnt = min(32, re - p);
        __syncthreads();
        if (c < cnt){ int e = csr[p+c]; s_eid[c] = e; s_src[c] = src[e]; }
        __syncthreads();
        for (int idx = c; idx < cnt*16; idx += 128){
            int j = idx >> 4, k = idx & 15;
            s_ea[idx] = ea_lin[(size_t)s_eid[j]*EDGED + k];
        }
        __syncthreads();
        for (int j = 0; j < cnt; ++j){
            acc += y[(size_t)s_src[j]*YCOLS + 128 + c];
            float ez = 0.f;
            #pragma unroll
            for (int k = 0; k < 16; ++k) ez += s_ea[j*16 + k] * W3[k*128 + c];
            acc += ez;
        }
    }
    float y1 = y[(size_t)i*YCOLS + c];
    float ys = y[(size_t)i*YCOLS + 256 + c];
    float outv = (float)deg * (y1 + b_nbr[c]) + acc + ys + b_self[c];
    out[(size_t)i*METAD + c] = outv;
}

// ---------------- launch ----------------

extern "C" void kernel_launch(void* const* d_in, const int* in_sizes, int n_in,
                              void* d_out, int out_size, void* d_ws, size_t ws_size,
                              hipStream_t stream){
    const float* node_feature    = (const float*)d_in[0];
    const float* edge_attr       = (const float*)d_in[1];
    const float* message_feature = (const float*)d_in[2];
    const int*   edge_index      = (const int*)d_in[3];
    const float* W_node = (const float*)d_in[4];
    const float* b_node = (const float*)d_in[5];
    const float* W_edge = (const float*)d_in[6];
    const float* b_edge = (const float*)d_in[7];
    const float* W_gat  = (const float*)d_in[8];
    const float* att_src= (const float*)d_in[9];
    const float* att_dst= (const float*)d_in[10];
    const float* b_gat  = (const float*)d_in[11];
    const float* W_nbr  = (const float*)d_in[12];
    const float* b_nbr  = (const float*)d_in[13];
    const float* W_self = (const float*)d_in[14];
    const float* b_self = (const float*)d_in[15];
    float* out = (float*)d_out;

    char* wsb = (char*)d_ws;
    size_t off = 0;
    auto walloc = [&](size_t bytes)->void*{
        void* p = wsb + off;
        off = (off + bytes + 511) & ~(size_t)511;
        return p;
    };
    unsigned short* h_bf  = (unsigned short*)walloc((size_t)N_NODES*GATD*2);   // 24.6 MB
    float* y              = (float*)walloc((size_t)N_NODES*YCOLS*4);           // 24.6 MB
    float* ea_lin         = (float*)walloc((size_t)N_EDGES*EDGED*4);           // 8.2 MB
    unsigned short* A_bf  = (unsigned short*)walloc((size_t)N_NODES*GATD*2);   // 24.6 MB
    unsigned short* x_bf  = (unsigned short*)walloc((size_t)N_NODES*METAIN*2); // 25.6 MB
    unsigned short* WgT   = (unsigned short*)walloc((size_t)GATD*GATD*2);      // 1.2 MB
    unsigned short* WcatT = (unsigned short*)walloc((size_t)YCOLS*METAIN*2);   // 0.6 MB
    float* a_src  = (float*)walloc((size_t)N_NODES*4);
    float* a_dst  = (float*)walloc((size_t)N_NODES*4);
    int* deg      = (int*)walloc((size_t)N_NODES*4);
    int* rowstart = (int*)walloc((size_t)(N_NODES+1)*4);
    int* cursor   = (int*)walloc((size_t)N_NODES*4);
    int* csr      = (int*)walloc((size_t)N_EDGES*4);

    const int* src = edge_index;
    const int* dst = edge_index + N_EDGES;

    hipMemsetAsync(deg, 0, (size_t)N_NODES*4, stream);

    // conversions
    conv_bf16_kernel<<<(N_NODES*GATD/8 + 255)/256, 256, 0, stream>>>(message_feature, A_bf, N_NODES*GATD/8);
    wgat_t_kernel<<<(GATD*GATD)/256, 256, 0, stream>>>(W_gat, WgT);
    wcat_t_kernel<<<(YCOLS*METAIN)/256, 256, 0, stream>>>(W_nbr, W_self, WcatT);

    ea_kernel<<<(N_EDGES*EDGED)/256, 256, 0, stream>>>(edge_attr, W_edge, b_edge, ea_lin);
    nf_kernel<<<(N_NODES*NODED)/256, 256, 0, stream>>>(node_feature, W_node, b_node, x_bf);
    deg_kernel<<<N_EDGES/256, 256, 0, stream>>>(dst, deg);
    scan_kernel<<<1, 1024, 0, stream>>>(deg, rowstart, cursor);
    csr_kernel<<<N_EDGES/256, 256, 0, stream>>>(dst, cursor, csr);

    // h_bf = bf16(mf @ W_gat)   [16000 x 768]
    mfma_gemm_kernel<true><<<dim3(GATD/128, N_NODES/128), 256, 0, stream>>>(A_bf, WgT, nullptr, h_bf, GATD, GATD);
    attn_dots_kernel<<<N_NODES/4, 256, 0, stream>>>(h_bf, att_src, att_dst, a_src, a_dst);
    gat_gather_kernel<<<N_NODES/4, 256, 0, stream>>>(h_bf, a_src, a_dst, b_gat, src, rowstart, csr, x_bf);

    // y = x @ Wcat   [16000 x 384]
    mfma_gemm_kernel<false><<<dim3(YCOLS/128, N_NODES/128), 256, 0, stream>>>(x_bf, WcatT, y, nullptr, YCOLS, METAIN);
    out_gather_kernel<<<N_NODES, 128, 0, stream>>>(y, ea_lin, W_nbr, b_nbr, b_self, src, rowstart, csr, out);
}

// Round 6
// 311.330 us; speedup vs baseline: 2.3385x; 1.0291x over previous
//
#include <hip/hip_runtime.h>

#define N_NODES 16000
#define N_EDGES 128000
#define GATD 768
#define NODED 32
#define EDGED 16
#define METAIN 800
#define METAD 128
#define YCOLS 384   // [y1 (128) | y2 (128) | yself (128)]

typedef short s16x8 __attribute__((ext_vector_type(8)));
typedef float f32x4v __attribute__((ext_vector_type(4)));

__device__ __forceinline__ unsigned short f2bf(float f){
    unsigned u = __float_as_uint(f);
    return (unsigned short)((u + 0x7fffu + ((u >> 16) & 1u)) >> 16);
}
__device__ __forceinline__ float us2f(unsigned short u){ return __uint_as_float(((unsigned)u)<<16); }

__device__ __forceinline__ void gload16(const void* g, void* l){
    __builtin_amdgcn_global_load_lds((const __attribute__((address_space(1))) void*)g,
                                     (__attribute__((address_space(3))) void*)l, 16, 0, 0);
}

// ---------------- merged weight pack ----------------
// blocks 0..143      : LDS-tiled transpose W_gat (768x768 f32) -> WgT (bf16, [c][k])
// blocks 144..1343   : WcatT[c][k] (384x800 bf16) from W_nbr/W_self
// block  1344        : W16 = W_edge @ W3 (16x128 f32), bb[c] = b_edge @ W3
__global__ __launch_bounds__(256) void pack_all_kernel(const float* __restrict__ W_gat,
                                                       const float* __restrict__ W_nbr,
                                                       const float* __restrict__ W_self,
                                                       const float* __restrict__ W_edge,
                                                       const float* __restrict__ b_edge,
                                                       unsigned short* __restrict__ WgT,
                                                       unsigned short* __restrict__ WcatT,
                                                       float* __restrict__ W16g,
                                                       float* __restrict__ bbg){
    int bid = blockIdx.x, tid = threadIdx.x;
    if (bid < 144){
        __shared__ float t[64][65];
        int bi = bid / 12, bj = bid % 12;
        int r16 = tid >> 4, c4 = (tid & 15) * 4;
        #pragma unroll
        for (int it = 0; it < 4; ++it){
            int row = it*16 + r16;
            float4 v = *reinterpret_cast<const float4*>(W_gat + (size_t)(bi*64+row)*GATD + bj*64 + c4);
            t[row][c4+0]=v.x; t[row][c4+1]=v.y; t[row][c4+2]=v.z; t[row][c4+3]=v.w;
        }
        __syncthreads();
        #pragma unroll
        for (int it = 0; it < 4; ++it){
            int row = it*16 + r16;   // output row = original column
            ushort4 o;
            o.x = f2bf(t[c4+0][row]); o.y = f2bf(t[c4+1][row]);
            o.z = f2bf(t[c4+2][row]); o.w = f2bf(t[c4+3][row]);
            *reinterpret_cast<ushort4*>(WgT + (size_t)(bj*64+row)*GATD + bi*64 + c4) = o;
        }
    } else if (bid < 1344){
        int idx = (bid-144)*256 + tid;               // < 384*800
        int c = idx / METAIN, k = idx % METAIN;
        float v;
        if (c < 128)      v = W_nbr[(size_t)k*METAD + c];
        else if (c < 256) v = W_nbr[(size_t)(800+k)*METAD + (c-128)];
        else              v = W_self[(size_t)k*METAD + (c-256)];
        WcatT[idx] = f2bf(v);
    } else {
        int c = tid;
        if (c < 128){
            float w3[16];
            #pragma unroll
            for (int k = 0; k < 16; ++k) w3[k] = W_nbr[(size_t)(1600+k)*METAD + c];
            #pragma unroll
            for (int j = 0; j < 16; ++j){
                float s = 0.f;
                #pragma unroll
                for (int k = 0; k < 16; ++k) s += W_edge[j*16+k] * w3[k];
                W16g[j*128 + c] = s;
            }
            float bb = 0.f;
            #pragma unroll
            for (int k = 0; k < 16; ++k) bb += b_edge[k] * w3[k];
            bbg[c] = bb;
        }
    }
}

// nf -> x_bf[:, 768:800] (bf16)
__global__ __launch_bounds__(256) void nf_kernel(const float* __restrict__ node_feature,
                                                 const float* __restrict__ W_node,
                                                 const float* __restrict__ b_node,
                                                 unsigned short* __restrict__ x_bf){
    __shared__ float Wn[1024];
    __shared__ float bn[32];
    int tid = threadIdx.x;
    for (int i = tid; i < 1024; i += 256) Wn[i] = W_node[i];
    if (tid < 32) bn[tid] = b_node[tid];
    __syncthreads();
    int idx = blockIdx.x*256 + tid;                  // < N*32
    int n = idx >> 5, j = idx & 31;
    const float* row = node_feature + (size_t)n*NODED;
    float s = bn[j];
    #pragma unroll
    for (int k = 0; k < 32; ++k) s += row[k] * Wn[k*32 + j];
    x_bf[(size_t)n*METAIN + GATD + j] = f2bf(s);
}

// ---------------- CSR build ----------------

__global__ __launch_bounds__(256) void deg_kernel(const int* __restrict__ dst, int* __restrict__ deg){
    int e = blockIdx.x*256 + threadIdx.x;
    atomicAdd(&deg[dst[e]], 1);
}

__global__ __launch_bounds__(1024) void scan_kernel(const int* __restrict__ deg,
                                                    int* __restrict__ rowstart,
                                                    int* __restrict__ cursor){
    __shared__ int part[1024];
    int t = threadIdx.x;
    int base = t * 16;
    int local[16];
    int s = 0;
    #pragma unroll
    for (int k = 0; k < 16; ++k){
        int idx = base + k;
        int v = (idx < N_NODES) ? deg[idx] : 0;
        local[k] = s; s += v;
    }
    part[t] = s;
    __syncthreads();
    for (int off = 1; off < 1024; off <<= 1){
        int v = 0;
        if (t >= off) v = part[t-off];
        __syncthreads();
        if (t >= off) part[t] += v;
        __syncthreads();
    }
    int excl = (t == 0) ? 0 : part[t-1];
    #pragma unroll
    for (int k = 0; k < 16; ++k){
        int idx = base + k;
        if (idx < N_NODES){ int rs = excl + local[k]; rowstart[idx] = rs; cursor[idx] = rs; }
    }
    if (t == 1023) rowstart[N_NODES] = part[1023];
}

__global__ __launch_bounds__(256) void csr_kernel(const int* __restrict__ dst,
                                                  int* __restrict__ cursor,
                                                  int* __restrict__ csr){
    int e = blockIdx.x*256 + threadIdx.x;
    int p = atomicAdd(&cursor[dst[e]], 1);
    csr[p] = e;
}

// ---------------- MFMA bf16 GEMM: C = A[M][K] @ Bt[Ncols][K]^T ----------------
// 128x128 tile, BK=32, 4 waves (2x2), each wave 64x64 = 4x4 frags of 16x16x32.
// AF32 : A source is f32, reg-staged + converted to bf16 on the fly (no conv pre-pass).
// DOTS : epilogue computes per-row dot with att_src/att_dst from f32 acc, atomicAdd.
// BFOUT: C written as bf16.

template<bool AF32, bool DOTS, bool BFOUT>
__global__ __launch_bounds__(256) void mfma_gemm_kernel(const float* __restrict__ A32,
                                                        const unsigned short* __restrict__ A16,
                                                        const unsigned short* __restrict__ Bt,
                                                        float* __restrict__ Cf,
                                                        unsigned short* __restrict__ Cb,
                                                        const float* __restrict__ att_src,
                                                        const float* __restrict__ att_dst,
                                                        float* __restrict__ a_srcO,
                                                        float* __restrict__ a_dstO,
                                                        int Ncols, int K){
    __shared__ __align__(16) unsigned short As[128*32];
    __shared__ __align__(16) unsigned short Bs[128*32];
    int tid = threadIdx.x;
    int wave = tid >> 6, lane = tid & 63;
    int rowBase = blockIdx.y * 128, colBase = blockIdx.x * 128;
    const float*          gA32p = AF32 ? A32 + (size_t)(rowBase + (tid>>2))*K + (tid&3)*8 : nullptr;
    const unsigned short* gA16p = AF32 ? nullptr : A16 + (size_t)(rowBase + (tid>>2))*K + (tid&3)*8;
    const unsigned short* gBp   = Bt + (size_t)(colBase + (tid>>2))*K + (tid&3)*8;
    char* lA = (char*)As + tid*16;
    char* lB = (char*)Bs + tid*16;
    int r0 = (wave>>1)*64, c0 = (wave&1)*64;
    int rl = lane & 15, koff = (lane>>4)*8;
    f32x4v acc[4][4] = {};
    for (int k0 = 0; k0 < K; k0 += 32){
        __syncthreads();                 // previous iter's LDS reads done
        gload16(gBp + k0,                  lB);
        gload16(gBp + (size_t)64*K + k0,   lB + 4096);
        if constexpr (AF32){
            float4 a0 = *reinterpret_cast<const float4*>(gA32p + k0);
            float4 a1 = *reinterpret_cast<const float4*>(gA32p + k0 + 4);
            float4 a2 = *reinterpret_cast<const float4*>(gA32p + (size_t)64*K + k0);
            float4 a3 = *reinterpret_cast<const float4*>(gA32p + (size_t)64*K + k0 + 4);
            union { unsigned short u[8]; s16x8 v; } p0, p1;
            p0.u[0]=f2bf(a0.x); p0.u[1]=f2bf(a0.y); p0.u[2]=f2bf(a0.z); p0.u[3]=f2bf(a0.w);
            p0.u[4]=f2bf(a1.x); p0.u[5]=f2bf(a1.y); p0.u[6]=f2bf(a1.z); p0.u[7]=f2bf(a1.w);
            p1.u[0]=f2bf(a2.x); p1.u[1]=f2bf(a2.y); p1.u[2]=f2bf(a2.z); p1.u[3]=f2bf(a2.w);
            p1.u[4]=f2bf(a3.x); p1.u[5]=f2bf(a3.y); p1.u[6]=f2bf(a3.z); p1.u[7]=f2bf(a3.w);
            *reinterpret_cast<s16x8*>(lA)        = p0.v;
            *reinterpret_cast<s16x8*>(lA + 4096) = p1.v;
        } else {
            gload16(gA16p + k0,                lA);
            gload16(gA16p + (size_t)64*K + k0, lA + 4096);
        }
        __syncthreads();                 // staging complete (vmcnt/lgkmcnt drained by compiler)
        s16x8 af[4], bfr[4];
        #pragma unroll
        for (int mi = 0; mi < 4; ++mi)
            af[mi] = *reinterpret_cast<const s16x8*>(&As[(r0 + mi*16 + rl)*32 + koff]);
        #pragma unroll
        for (int ni = 0; ni < 4; ++ni)
            bfr[ni] = *reinterpret_cast<const s16x8*>(&Bs[(c0 + ni*16 + rl)*32 + koff]);
        #pragma unroll
        for (int mi = 0; mi < 4; ++mi)
            #pragma unroll
            for (int ni = 0; ni < 4; ++ni)
                acc[mi][ni] = __builtin_amdgcn_mfma_f32_16x16x32_bf16(af[mi], bfr[ni], acc[mi][ni], 0, 0, 0);
    }
    int orow = rowBase + r0 + (lane>>4)*4;
    int ocol = colBase + c0 + rl;
    #pragma unroll
    for (int mi = 0; mi < 4; ++mi)
        #pragma unroll
        for (int ni = 0; ni < 4; ++ni){
            #pragma unroll
            for (int j = 0; j < 4; ++j){
                size_t idx = (size_t)(orow + mi*16 + j)*Ncols + ocol + ni*16;
                if constexpr (BFOUT) Cb[idx] = f2bf(acc[mi][ni][j]);
                else                 Cf[idx] = acc[mi][ni][j];
            }
        }
    if constexpr (DOTS){
        float as_c[4], ad_c[4];
        #pragma unroll
        for (int ni = 0; ni < 4; ++ni){
            int col = colBase + c0 + ni*16 + rl;
            as_c[ni] = att_src[col];
            ad_c[ni] = att_dst[col];
        }
        #pragma unroll
        for (int mi = 0; mi < 4; ++mi)
            #pragma unroll
            for (int j = 0; j < 4; ++j){
                float ps = 0.f, pd = 0.f;
                #pragma unroll
                for (int ni = 0; ni < 4; ++ni){
                    float v = acc[mi][ni][j];
                    ps += v * as_c[ni];
                    pd += v * ad_c[ni];
                }
                #pragma unroll
                for (int off = 8; off; off >>= 1){
                    ps += __shfl_xor(ps, off);
                    pd += __shfl_xor(pd, off);
                }
                if (rl == 0){
                    int r = rowBase + r0 + mi*16 + (lane>>4)*4 + j;
                    atomicAdd(&a_srcO[r], ps);
                    atomicAdd(&a_dstO[r], pd);
                }
            }
    }
}

// ---------------- GAT aggregate: wave per node, fused edge-softmax ----------------
// (max-subtraction skipped: |alpha| << 1 so exp is safe; mathematically identical)

__global__ __launch_bounds__(256) void gat_gather_kernel(const unsigned short* __restrict__ h_bf,
                                                         const float* __restrict__ a_src,
                                                         const float* __restrict__ a_dst,
                                                         const float* __restrict__ b_gat,
                                                         const int* __restrict__ src,
                                                         const int* __restrict__ rowstart,
                                                         const int* __restrict__ csr,
                                                         unsigned short* __restrict__ x_bf){
    int wv = threadIdx.x >> 6, lane = threadIdx.x & 63;
    int i = blockIdx.x*4 + wv;
    float adi = a_dst[i];
    float al = a_src[i] + adi;
    al = al > 0.f ? al : 0.2f*al;
    float ex_self = expf(al);
    const unsigned short* hi = h_bf + (size_t)i*GATD;
    float acc[12];
    #pragma unroll
    for (int c = 0; c < 3; ++c){
        ushort4 v = *reinterpret_cast<const ushort4*>(hi + c*256 + lane*4);
        acc[c*4+0] = ex_self*us2f(v.x); acc[c*4+1] = ex_self*us2f(v.y);
        acc[c*4+2] = ex_self*us2f(v.z); acc[c*4+3] = ex_self*us2f(v.w);
    }
    float dsum = ex_self;
    int rs = rowstart[i], re = rowstart[i+1];
    for (int p = rs; p < re; p += 64){
        int cnt = min(64, re - p);
        int sv = 0; float ev = 0.f;
        if (lane < cnt){
            int e = csr[p+lane];
            sv = src[e];
            float a = a_src[sv] + adi;
            a = a > 0.f ? a : 0.2f*a;
            ev = expf(a);
        }
        for (int j = 0; j < cnt; ++j){
            int   ss = __shfl(sv, j);
            float ww = __shfl(ev, j);
            dsum += ww;
            const unsigned short* hs = h_bf + (size_t)ss*GATD;
            #pragma unroll
            for (int c = 0; c < 3; ++c){
                ushort4 v = *reinterpret_cast<const ushort4*>(hs + c*256 + lane*4);
                acc[c*4+0] += ww*us2f(v.x); acc[c*4+1] += ww*us2f(v.y);
                acc[c*4+2] += ww*us2f(v.z); acc[c*4+3] += ww*us2f(v.w);
            }
        }
    }
    float inv = 1.f / dsum;
    unsigned short* xr = x_bf + (size_t)i*METAIN;
    #pragma unroll
    for (int c = 0; c < 3; ++c){
        float4 bg = *reinterpret_cast<const float4*>(b_gat + c*256 + lane*4);
        ushort4 o;
        o.x = f2bf(acc[c*4+0]*inv + bg.x); o.y = f2bf(acc[c*4+1]*inv + bg.y);
        o.z = f2bf(acc[c*4+2]*inv + bg.z); o.w = f2bf(acc[c*4+3]*inv + bg.w);
        *reinterpret_cast<ushort4*>(xr + c*256 + lane*4) = o;
    }
}

// ---------------- final aggregation (ez folded: ez = edge_attr@W16 + bb) ----------------
// out[i][c] = deg*(y1[i][c]+b_nbr[c]+bb[c]) + sum_e (y2[src_e][c] + edge_attr[e]@W16[:,c]) + yself[i][c] + b_self[c]

__global__ __launch_bounds__(128) void out_gather_kernel(const float* __restrict__ y,
                                                         const float* __restrict__ edge_attr,
                                                         const float* __restrict__ W16g,
                                                         const float* __restrict__ bbg,
                                                         const float* __restrict__ b_nbr,
                                                         const float* __restrict__ b_self,
                                                         const int* __restrict__ src,
                                                         const int* __restrict__ rowstart,
                                                         const int* __restrict__ csr,
                                                         float* __restrict__ out){
    __shared__ float W3[16*128];
    __shared__ int   s_src[32];
    __shared__ int   s_eid[32];
    __shared__ float s_ea[32*16];
    int i = blockIdx.x, c = threadIdx.x;
    #pragma unroll
    for (int k = 0; k < 16; ++k) W3[k*128 + c] = W16g[k*128 + c];
    int rs = rowstart[i], re = rowstart[i+1];
    int deg = re - rs;
    float acc = 0.f;
    for (int p = rs; p < re; p += 32){
        int cnt = min(32, re - p);
        __syncthreads();
        if (c < cnt){ int e = csr[p+c]; s_eid[c] = e; s_src[c] = src[e]; }
        __syncthreads();
        for (int idx = c; idx < cnt*16; idx += 128){
            int j = idx >> 4, k = idx & 15;
            s_ea[idx] = edge_attr[(size_t)s_eid[j]*EDGED + k];
        }
        __syncthreads();
        for (int j = 0; j < cnt; ++j){
            acc += y[(size_t)s_src[j]*YCOLS + 128 + c];
            float ez = 0.f;
            #pragma unroll
            for (int k = 0; k < 16; ++k) ez += s_ea[j*16 + k] * W3[k*128 + c];
            acc += ez;
        }
    }
    float y1 = y[(size_t)i*YCOLS + c];
    float ys = y[(size_t)i*YCOLS + 256 + c];
    float outv = (float)deg * (y1 + b_nbr[c] + bbg[c]) + acc + ys + b_self[c];
    out[(size_t)i*METAD + c] = outv;
}

// ---------------- launch ----------------

extern "C" void kernel_launch(void* const* d_in, const int* in_sizes, int n_in,
                              void* d_out, int out_size, void* d_ws, size_t ws_size,
                              hipStream_t stream){
    const float* node_feature    = (const float*)d_in[0];
    const float* edge_attr       = (const float*)d_in[1];
    const float* message_feature = (const float*)d_in[2];
    const int*   edge_index      = (const int*)d_in[3];
    const float* W_node = (const float*)d_in[4];
    const float* b_node = (const float*)d_in[5];
    const float* W_edge = (const float*)d_in[6];
    const float* b_edge = (const float*)d_in[7];
    const float* W_gat  = (const float*)d_in[8];
    const float* att_src= (const float*)d_in[9];
    const float* att_dst= (const float*)d_in[10];
    const float* b_gat  = (const float*)d_in[11];
    const float* W_nbr  = (const float*)d_in[12];
    const float* b_nbr  = (const float*)d_in[13];
    const float* W_self = (const float*)d_in[14];
    const float* b_self = (const float*)d_in[15];
    float* out = (float*)d_out;

    char* wsb = (char*)d_ws;
    size_t off = 0;
    auto walloc = [&](size_t bytes)->void*{
        void* p = wsb + off;
        off = (off + bytes + 511) & ~(size_t)511;
        return p;
    };
    unsigned short* h_bf  = (unsigned short*)walloc((size_t)N_NODES*GATD*2);   // 24.6 MB
    float* y              = (float*)walloc((size_t)N_NODES*YCOLS*4);           // 24.6 MB
    unsigned short* x_bf  = (unsigned short*)walloc((size_t)N_NODES*METAIN*2); // 25.6 MB
    unsigned short* WgT   = (unsigned short*)walloc((size_t)GATD*GATD*2);      // 1.2 MB
    unsigned short* WcatT = (unsigned short*)walloc((size_t)YCOLS*METAIN*2);   // 0.6 MB
    float* W16g   = (float*)walloc(16*128*4);
    float* bbg    = (float*)walloc(128*4);
    float* zbase  = (float*)walloc((size_t)3*N_NODES*4);   // [a_src | a_dst | deg] contiguous
    float* a_src  = zbase;
    float* a_dst  = zbase + N_NODES;
    int*   deg    = (int*)(zbase + 2*N_NODES);
    int* rowstart = (int*)walloc((size_t)(N_NODES+1)*4);
    int* cursor   = (int*)walloc((size_t)N_NODES*4);
    int* csr      = (int*)walloc((size_t)N_EDGES*4);

    const int* src = edge_index;
    const int* dst = edge_index + N_EDGES;

    hipMemsetAsync(zbase, 0, (size_t)3*N_NODES*4, stream);

    pack_all_kernel<<<1345, 256, 0, stream>>>(W_gat, W_nbr, W_self, W_edge, b_edge,
                                              WgT, WcatT, W16g, bbg);
    nf_kernel<<<(N_NODES*NODED)/256, 256, 0, stream>>>(node_feature, W_node, b_node, x_bf);
    deg_kernel<<<N_EDGES/256, 256, 0, stream>>>(dst, deg);
    scan_kernel<<<1, 1024, 0, stream>>>((const int*)deg, rowstart, cursor);
    csr_kernel<<<N_EDGES/256, 256, 0, stream>>>(dst, cursor, csr);

    // h_bf = bf16(mf @ W_gat), fused attention dots (a_src/a_dst via atomics)
    mfma_gemm_kernel<true,true,true><<<dim3(GATD/128, N_NODES/128), 256, 0, stream>>>(
        message_feature, nullptr, WgT, nullptr, h_bf, att_src, att_dst, a_src, a_dst, GATD, GATD);

    gat_gather_kernel<<<N_NODES/4, 256, 0, stream>>>(h_bf, a_src, a_dst, b_gat, src, rowstart, csr, x_bf);

    // y = x @ Wcat   [16000 x 384]
    mfma_gemm_kernel<false,false,false><<<dim3(YCOLS/128, N_NODES/128), 256, 0, stream>>>(
        nullptr, x_bf, WcatT, y, nullptr, nullptr, nullptr, nullptr, nullptr, YCOLS, METAIN);

    out_gather_kernel<<<N_NODES, 128, 0, stream>>>(y, edge_attr, W16g, bbg, b_nbr, b_self,
                                                   src, rowstart, csr, out);
}

// Round 8
// 305.581 us; speedup vs baseline: 2.3825x; 1.0188x over previous
//
#include <hip/hip_runtime.h>

#define N_NODES 16000
#define N_EDGES 128000
#define GATD 768
#define NODED 32
#define EDGED 16
#define METAIN 800
#define METAD 128
#define YCOLS 384   // [y1 (128) | y2 (128) | yself (128)]

typedef short s16x8 __attribute__((ext_vector_type(8)));
typedef float f32x4v __attribute__((ext_vector_type(4)));

__device__ __forceinline__ unsigned short f2bf(float f){
    unsigned u = __float_as_uint(f);
    return (unsigned short)((u + 0x7fffu + ((u >> 16) & 1u)) >> 16);
}
__device__ __forceinline__ float us2f(unsigned short u){ return __uint_as_float(((unsigned)u)<<16); }

__device__ __forceinline__ void gload16(const void* g, void* l){
    __builtin_amdgcn_global_load_lds((const __attribute__((address_space(1))) void*)g,
                                     (__attribute__((address_space(3))) void*)l, 16, 0, 0);
}

// ---------------- bf16 conversion pre-pass ----------------

__global__ __launch_bounds__(256) void conv_bf16_kernel(const float* __restrict__ in,
                                                        unsigned short* __restrict__ out, int n8){
    int i = blockIdx.x*256 + threadIdx.x;
    if (i >= n8) return;
    const float4* p = reinterpret_cast<const float4*>(in) + (size_t)i*2;
    float4 a = p[0], b = p[1];
    union { unsigned short u[8]; s16x8 v; } o;
    o.u[0]=f2bf(a.x); o.u[1]=f2bf(a.y); o.u[2]=f2bf(a.z); o.u[3]=f2bf(a.w);
    o.u[4]=f2bf(b.x); o.u[5]=f2bf(b.y); o.u[6]=f2bf(b.z); o.u[7]=f2bf(b.w);
    reinterpret_cast<s16x8*>(out)[i] = o.v;
}

// ---------------- merged weight pack ----------------
// blocks 0..143    : LDS-tiled transpose W_gat (768x768 f32) -> WgT (bf16, [c][k])
// blocks 144..1343 : WcatT[c][k] (384x800 bf16) from W_nbr/W_self
// block  1344      : W16 = W_edge @ W3 (16x128 f32), bb[c] = b_edge @ W3
__global__ __launch_bounds__(256) void pack_all_kernel(const float* __restrict__ W_gat,
                                                       const float* __restrict__ W_nbr,
                                                       const float* __restrict__ W_self,
                                                       const float* __restrict__ W_edge,
                                                       const float* __restrict__ b_edge,
                                                       unsigned short* __restrict__ WgT,
                                                       unsigned short* __restrict__ WcatT,
                                                       float* __restrict__ W16g,
                                                       float* __restrict__ bbg){
    int bid = blockIdx.x, tid = threadIdx.x;
    if (bid < 144){
        __shared__ float t[64][65];
        int bi = bid / 12, bj = bid % 12;
        int r16 = tid >> 4, c4 = (tid & 15) * 4;
        #pragma unroll
        for (int it = 0; it < 4; ++it){
            int row = it*16 + r16;
            float4 v = *reinterpret_cast<const float4*>(W_gat + (size_t)(bi*64+row)*GATD + bj*64 + c4);
            t[row][c4+0]=v.x; t[row][c4+1]=v.y; t[row][c4+2]=v.z; t[row][c4+3]=v.w;
        }
        __syncthreads();
        #pragma unroll
        for (int it = 0; it < 4; ++it){
            int row = it*16 + r16;   // output row = original column
            ushort4 o;
            o.x = f2bf(t[c4+0][row]); o.y = f2bf(t[c4+1][row]);
            o.z = f2bf(t[c4+2][row]); o.w = f2bf(t[c4+3][row]);
            *reinterpret_cast<ushort4*>(WgT + (size_t)(bj*64+row)*GATD + bi*64 + c4) = o;
        }
    } else if (bid < 1344){
        int idx = (bid-144)*256 + tid;               // < 384*800
        int c = idx / METAIN, k = idx % METAIN;
        float v;
        if (c < 128)      v = W_nbr[(size_t)k*METAD + c];
        else if (c < 256) v = W_nbr[(size_t)(800+k)*METAD + (c-128)];
        else              v = W_self[(size_t)k*METAD + (c-256)];
        WcatT[idx] = f2bf(v);
    } else {
        int c = tid;
        if (c < 128){
            float w3[16];
            #pragma unroll
            for (int k = 0; k < 16; ++k) w3[k] = W_nbr[(size_t)(1600+k)*METAD + c];
            #pragma unroll
            for (int j = 0; j < 16; ++j){
                float s = 0.f;
                #pragma unroll
                for (int k = 0; k < 16; ++k) s += W_edge[j*16+k] * w3[k];
                W16g[j*128 + c] = s;
            }
            float bb = 0.f;
            #pragma unroll
            for (int k = 0; k < 16; ++k) bb += b_edge[k] * w3[k];
            bbg[c] = bb;
        }
    }
}

// nf -> x_bf[:, 768:800] (bf16)
__global__ __launch_bounds__(256) void nf_kernel(const float* __restrict__ node_feature,
                                                 const float* __restrict__ W_node,
                                                 const float* __restrict__ b_node,
                                                 unsigned short* __restrict__ x_bf){
    __shared__ float Wn[1024];
    __shared__ float bn[32];
    int tid = threadIdx.x;
    for (int i = tid; i < 1024; i += 256) Wn[i] = W_node[i];
    if (tid < 32) bn[tid] = b_node[tid];
    __syncthreads();
    int idx = blockIdx.x*256 + tid;                  // < N*32
    int n = idx >> 5, j = idx & 31;
    const float* row = node_feature + (size_t)n*NODED;
    float s = bn[j];
    #pragma unroll
    for (int k = 0; k < 32; ++k) s += row[k] * Wn[k*32 + j];
    x_bf[(size_t)n*METAIN + GATD + j] = f2bf(s);
}

// ---------------- CSR build ----------------

__global__ __launch_bounds__(256) void deg_kernel(const int* __restrict__ dst, int* __restrict__ deg){
    int e = blockIdx.x*256 + threadIdx.x;
    atomicAdd(&deg[dst[e]], 1);
}

__global__ __launch_bounds__(1024) void scan_kernel(const int* __restrict__ deg,
                                                    int* __restrict__ rowstart,
                                                    int* __restrict__ cursor){
    __shared__ int part[1024];
    int t = threadIdx.x;
    int base = t * 16;
    int local[16];
    int s = 0;
    #pragma unroll
    for (int k = 0; k < 16; ++k){
        int idx = base + k;
        int v = (idx < N_NODES) ? deg[idx] : 0;
        local[k] = s; s += v;
    }
    part[t] = s;
    __syncthreads();
    for (int off = 1; off < 1024; off <<= 1){
        int v = 0;
        if (t >= off) v = part[t-off];
        __syncthreads();
        if (t >= off) part[t] += v;
        __syncthreads();
    }
    int excl = (t == 0) ? 0 : part[t-1];
    #pragma unroll
    for (int k = 0; k < 16; ++k){
        int idx = base + k;
        if (idx < N_NODES){ int rs = excl + local[k]; rowstart[idx] = rs; cursor[idx] = rs; }
    }
    if (t == 1023) rowstart[N_NODES] = part[1023];
}

__global__ __launch_bounds__(256) void csr_kernel(const int* __restrict__ dst,
                                                  int* __restrict__ cursor,
                                                  int* __restrict__ csr){
    int e = blockIdx.x*256 + threadIdx.x;
    int p = atomicAdd(&cursor[dst[e]], 1);
    csr[p] = e;
}

// ---------------- MFMA bf16 GEMM: C = A[M][K] @ Bt[Ncols][K]^T ----------------
// 128x128 tile, BK=32, 512 threads = 8 waves (2 row x 4 col), each wave 64x32 (4x2 frags).
// grid: blockIdx.x = row block (fastest -> consecutive blocks share L2-resident B panel,
//        A panels streamed once), blockIdx.y = col block.
// DOTS : epilogue computes per-row dot with att_src/att_dst from f32 acc, atomicAdd.
// BFOUT: C written as bf16.

template<bool DOTS, bool BFOUT>
__global__ __launch_bounds__(512) void mfma_gemm_kernel(const unsigned short* __restrict__ A,
                                                        const unsigned short* __restrict__ Bt,
                                                        float* __restrict__ Cf,
                                                        unsigned short* __restrict__ Cb,
                                                        const float* __restrict__ att_src,
                                                        const float* __restrict__ att_dst,
                                                        float* __restrict__ a_srcO,
                                                        float* __restrict__ a_dstO,
                                                        int Ncols, int K){
    __shared__ __align__(16) unsigned short As[128*32];
    __shared__ __align__(16) unsigned short Bs[128*32];
    int tid = threadIdx.x;
    int wave = tid >> 6, lane = tid & 63;
    int rowBase = blockIdx.x * 128, colBase = blockIdx.y * 128;
    // one 16B chunk of A and one of B per thread per K-step
    const unsigned short* gA = A  + (size_t)(rowBase + (tid>>2))*K + (tid&3)*8;
    const unsigned short* gB = Bt + (size_t)(colBase + (tid>>2))*K + (tid&3)*8;
    char* lA = (char*)As + tid*16;
    char* lB = (char*)Bs + tid*16;
    int r0 = (wave>>2)*64, c0 = (wave&3)*32;
    int rl = lane & 15, koff = (lane>>4)*8;
    f32x4v acc[4][2] = {};
    for (int k0 = 0; k0 < K; k0 += 32){
        __syncthreads();                 // previous iter's LDS reads done
        gload16(gA + k0, lA);
        gload16(gB + k0, lB);
        __syncthreads();                 // staging complete (compiler drains vmcnt)
        s16x8 af[4], bfr[2];
        #pragma unroll
        for (int mi = 0; mi < 4; ++mi)
            af[mi] = *reinterpret_cast<const s16x8*>(&As[(r0 + mi*16 + rl)*32 + koff]);
        #pragma unroll
        for (int ni = 0; ni < 2; ++ni)
            bfr[ni] = *reinterpret_cast<const s16x8*>(&Bs[(c0 + ni*16 + rl)*32 + koff]);
        #pragma unroll
        for (int mi = 0; mi < 4; ++mi)
            #pragma unroll
            for (int ni = 0; ni < 2; ++ni)
                acc[mi][ni] = __builtin_amdgcn_mfma_f32_16x16x32_bf16(af[mi], bfr[ni], acc[mi][ni], 0, 0, 0);
    }
    int orow = rowBase + r0 + (lane>>4)*4;
    int ocol = colBase + c0 + rl;
    #pragma unroll
    for (int mi = 0; mi < 4; ++mi)
        #pragma unroll
        for (int ni = 0; ni < 2; ++ni){
            #pragma unroll
            for (int j = 0; j < 4; ++j){
                size_t idx = (size_t)(orow + mi*16 + j)*Ncols + ocol + ni*16;
                if constexpr (BFOUT) Cb[idx] = f2bf(acc[mi][ni][j]);
                else                 Cf[idx] = acc[mi][ni][j];
            }
        }
    if constexpr (DOTS){
        float as_c[2], ad_c[2];
        #pragma unroll
        for (int ni = 0; ni < 2; ++ni){
            int col = colBase + c0 + ni*16 + rl;
            as_c[ni] = att_src[col];
            ad_c[ni] = att_dst[col];
        }
        #pragma unroll
        for (int mi = 0; mi < 4; ++mi)
            #pragma unroll
            for (int j = 0; j < 4; ++j){
                float ps = 0.f, pd = 0.f;
                #pragma unroll
                for (int ni = 0; ni < 2; ++ni){
                    float v = acc[mi][ni][j];
                    ps += v * as_c[ni];
                    pd += v * ad_c[ni];
                }
                #pragma unroll
                for (int off = 8; off; off >>= 1){
                    ps += __shfl_xor(ps, off);
                    pd += __shfl_xor(pd, off);
                }
                if (rl == 0){
                    int r = rowBase + r0 + mi*16 + (lane>>4)*4 + j;
                    atomicAdd(&a_srcO[r], ps);
                    atomicAdd(&a_dstO[r], pd);
                }
            }
    }
}

// ---------------- GAT aggregate: wave per node, fused edge-softmax ----------------
// (max-subtraction skipped: |alpha| << 1 so exp is safe; mathematically identical)

__global__ __launch_bounds__(256) void gat_gather_kernel(const unsigned short* __restrict__ h_bf,
                                                         const float* __restrict__ a_src,
                                                         const float* __restrict__ a_dst,
                                                         const float* __restrict__ b_gat,
                                                         const int* __restrict__ src,
                                                         const int* __restrict__ rowstart,
                                                         const int* __restrict__ csr,
                                                         unsigned short* __restrict__ x_bf){
    int wv = threadIdx.x >> 6, lane = threadIdx.x & 63;
    int i = blockIdx.x*4 + wv;
    float adi = a_dst[i];
    float al = a_src[i] + adi;
    al = al > 0.f ? al : 0.2f*al;
    float ex_self = expf(al);
    const unsigned short* hi = h_bf + (size_t)i*GATD;
    float acc[12];
    #pragma unroll
    for (int c = 0; c < 3; ++c){
        ushort4 v = *reinterpret_cast<const ushort4*>(hi + c*256 + lane*4);
        acc[c*4+0] = ex_self*us2f(v.x); acc[c*4+1] = ex_self*us2f(v.y);
        acc[c*4+2] = ex_self*us2f(v.z); acc[c*4+3] = ex_self*us2f(v.w);
    }
    float dsum = ex_self;
    int rs = rowstart[i], re = rowstart[i+1];
    for (int p = rs; p < re; p += 64){
        int cnt = min(64, re - p);
        int sv = 0; float ev = 0.f;
        if (lane < cnt){
            int e = csr[p+lane];
            sv = src[e];
            float a = a_src[sv] + adi;
            a = a > 0.f ? a : 0.2f*a;
            ev = expf(a);
        }
        for (int j = 0; j < cnt; ++j){
            int   ss = __shfl(sv, j);
            float ww = __shfl(ev, j);
            dsum += ww;
            const unsigned short* hs = h_bf + (size_t)ss*GATD;
            #pragma unroll
            for (int c = 0; c < 3; ++c){
                ushort4 v = *reinterpret_cast<const ushort4*>(hs + c*256 + lane*4);
                acc[c*4+0] += ww*us2f(v.x); acc[c*4+1] += ww*us2f(v.y);
                acc[c*4+2] += ww*us2f(v.z); acc[c*4+3] += ww*us2f(v.w);
            }
        }
    }
    float inv = 1.f / dsum;
    unsigned short* xr = x_bf + (size_t)i*METAIN;
    #pragma unroll
    for (int c = 0; c < 3; ++c){
        float4 bg = *reinterpret_cast<const float4*>(b_gat + c*256 + lane*4);
        ushort4 o;
        o.x = f2bf(acc[c*4+0]*inv + bg.x); o.y = f2bf(acc[c*4+1]*inv + bg.y);
        o.z = f2bf(acc[c*4+2]*inv + bg.z); o.w = f2bf(acc[c*4+3]*inv + bg.w);
        *reinterpret_cast<ushort4*>(xr + c*256 + lane*4) = o;
    }
}

// ---------------- final aggregation (ez folded: ez = edge_attr@W16 + bb) ----------------

__global__ __launch_bounds__(128) void out_gather_kernel(const float* __restrict__ y,
                                                         const float* __restrict__ edge_attr,
                                                         const float* __restrict__ W16g,
                                                         const float* __restrict__ bbg,
                                                         const float* __restrict__ b_nbr,
                                                         const float* __restrict__ b_self,
                                                         const int* __restrict__ src,
                                                         const int* __restrict__ rowstart,
                                                         const int* __restrict__ csr,
                                                         float* __restrict__ out){
    __shared__ float W3[16*128];
    __shared__ int   s_src[32];
    __shared__ int   s_eid[32];
    __shared__ float s_ea[32*16];
    int i = blockIdx.x, c = threadIdx.x;
    #pragma unroll
    for (int k = 0; k < 16; ++k) W3[k*128 + c] = W16g[k*128 + c];
    int rs = rowstart[i], re = rowstart[i+1];
    int deg = re - rs;
    float acc = 0.f;
    for (int p = rs; p < re; p += 32){
        int cnt = min(32, re - p);
        __syncthreads();
        if (c < cnt){ int e = csr[p+c]; s_eid[c] = e; s_src[c] = src[e]; }
        __syncthreads();
        for (int idx = c; idx < cnt*16; idx += 128){
            int j = idx >> 4, k = idx & 15;
            s_ea[idx] = edge_attr[(size_t)s_eid[j]*EDGED + k];
        }
        __syncthreads();
        for (int j = 0; j < cnt; ++j){
            acc += y[(size_t)s_src[j]*YCOLS + 128 + c];
            float ez = 0.f;
            #pragma unroll
            for (int k = 0; k < 16; ++k) ez += s_ea[j*16 + k] * W3[k*128 + c];
            acc += ez;
        }
    }
    float y1 = y[(size_t)i*YCOLS + c];
    float ys = y[(size_t)i*YCOLS + 256 + c];
    float outv = (float)deg * (y1 + b_nbr[c] + bbg[c]) + acc + ys + b_self[c];
    out[(size_t)i*METAD + c] = outv;
}

// ---------------- launch ----------------

extern "C" void kernel_launch(void* const* d_in, const int* in_sizes, int n_in,
                              void* d_out, int out_size, void* d_ws, size_t ws_size,
                              hipStream_t stream){
    const float* node_feature    = (const float*)d_in[0];
    const float* edge_attr       = (const float*)d_in[1];
    const float* message_feature = (const float*)d_in[2];
    const int*   edge_index      = (const int*)d_in[3];
    const float* W_node = (const float*)d_in[4];
    const float* b_node = (const float*)d_in[5];
    const float* W_edge = (const float*)d_in[6];
    const float* b_edge = (const float*)d_in[7];
    const float* W_gat  = (const float*)d_in[8];
    const float* att_src= (const float*)d_in[9];
    const float* att_dst= (const float*)d_in[10];
    const float* b_gat  = (const float*)d_in[11];
    const float* W_nbr  = (const float*)d_in[12];
    const float* b_nbr  = (const float*)d_in[13];
    const float* W_self = (const float*)d_in[14];
    const float* b_self = (const float*)d_in[15];
    float* out = (float*)d_out;

    char* wsb = (char*)d_ws;
    size_t off = 0;
    auto walloc = [&](size_t bytes)->void*{
        void* p = wsb + off;
        off = (off + bytes + 511) & ~(size_t)511;
        return p;
    };
    unsigned short* h_bf  = (unsigned short*)walloc((size_t)N_NODES*GATD*2);   // 24.6 MB
    float* y              = (float*)walloc((size_t)N_NODES*YCOLS*4);           // 24.6 MB
    unsigned short* A_bf  = (unsigned short*)walloc((size_t)N_NODES*GATD*2);   // 24.6 MB
    unsigned short* x_bf  = (unsigned short*)walloc((size_t)N_NODES*METAIN*2); // 25.6 MB
    unsigned short* WgT   = (unsigned short*)walloc((size_t)GATD*GATD*2);      // 1.2 MB
    unsigned short* WcatT = (unsigned short*)walloc((size_t)YCOLS*METAIN*2);   // 0.6 MB
    float* W16g   = (float*)walloc(16*128*4);
    float* bbg    = (float*)walloc(128*4);
    float* zbase  = (float*)walloc((size_t)3*N_NODES*4);   // [a_src | a_dst | deg] contiguous
    float* a_src  = zbase;
    float* a_dst  = zbase + N_NODES;
    int*   deg    = (int*)(zbase + 2*N_NODES);
    int* rowstart = (int*)walloc((size_t)(N_NODES+1)*4);
    int* cursor   = (int*)walloc((size_t)N_NODES*4);
    int* csr      = (int*)walloc((size_t)N_EDGES*4);

    const int* src = edge_index;
    const int* dst = edge_index + N_EDGES;

    hipMemsetAsync(zbase, 0, (size_t)3*N_NODES*4, stream);

    conv_bf16_kernel<<<(N_NODES*GATD/8 + 255)/256, 256, 0, stream>>>(message_feature, A_bf, N_NODES*GATD/8);
    pack_all_kernel<<<1345, 256, 0, stream>>>(W_gat, W_nbr, W_self, W_edge, b_edge,
                                              WgT, WcatT, W16g, bbg);
    nf_kernel<<<(N_NODES*NODED)/256, 256, 0, stream>>>(node_feature, W_node, b_node, x_bf);
    deg_kernel<<<N_EDGES/256, 256, 0, stream>>>(dst, deg);
    scan_kernel<<<1, 1024, 0, stream>>>((const int*)deg, rowstart, cursor);
    csr_kernel<<<N_EDGES/256, 256, 0, stream>>>(dst, cursor, csr);

    // h_bf = bf16(mf @ W_gat), fused attention dots (a_src/a_dst via atomics)
    mfma_gemm_kernel<true,true><<<dim3(N_NODES/128, GATD/128), 512, 0, stream>>>(
        A_bf, WgT, nullptr, h_bf, att_src, att_dst, a_src, a_dst, GATD, GATD);

    gat_gather_kernel<<<N_NODES/4, 256, 0, stream>>>(h_bf, a_src, a_dst, b_gat, src, rowstart, csr, x_bf);

    // y = x @ Wcat   [16000 x 384]
    mfma_gemm_kernel<false,false><<<dim3(N_NODES/128, YCOLS/128), 512, 0, stream>>>(
        x_bf, WcatT, y, nullptr, nullptr, nullptr, nullptr, nullptr, YCOLS, METAIN);

    out_gather_kernel<<<N_NODES, 128, 0, stream>>>(y, edge_attr, W16g, bbg, b_nbr, b_self,
                                                   src, rowstart, csr, out);
}